// Round 15
// baseline (265.731 us; speedup 1.0000x reference)
//
#include <hip/hip_runtime.h>
#include <cstddef>

// Problem constants: S=8, B=32, D=5, T=30, E=768, H=128, 4H=512.

typedef __attribute__((ext_vector_type(8))) _Float16 f16x8;
typedef __attribute__((ext_vector_type(4))) _Float16 f16x4;
typedef __attribute__((ext_vector_type(2))) _Float16 f16x2;
typedef __attribute__((ext_vector_type(4))) float f32x4;

__device__ __forceinline__ float rcp_(float x) { return __builtin_amdgcn_rcpf(x); }
__device__ __forceinline__ float sigf(float x) { return rcp_(1.0f + __expf(-x)); }
__device__ __forceinline__ float tanhf_(float x) { return 1.0f - 2.0f * rcp_(__expf(2.0f * x) + 1.0f); }

// LDS-only barrier: drains lgkmcnt but NOT vmcnt (global ops stay in flight).
__device__ __forceinline__ void barrier_lds_only() {
  asm volatile("s_waitcnt lgkmcnt(0)" ::: "memory");
  __builtin_amdgcn_s_barrier();
  __builtin_amdgcn_sched_barrier(0);
}

// ---------------------------------------------------------------------------
// K0r: per-stock compacted row map: rows (n,t) with t < len[s,n].
// ---------------------------------------------------------------------------
__global__ __launch_bounds__(256) void k0_rowmap(const int* __restrict__ lens,
                                                 int* __restrict__ rowmap,
                                                 int* __restrict__ Ms) {
  const int s = blockIdx.x;
  const int tid = threadIdx.x;
  __shared__ int st[160];
  __shared__ int ln[160];
  if (tid < 160) {
    const int b = tid / 5, d = tid % 5;
    ln[tid] = lens[(b * 8 + s) * 5 + d];
  }
  __syncthreads();
  if (tid == 0) {
    int run = 0;
    for (int n = 0; n < 160; ++n) { st[n] = run; run += ln[n]; }
    Ms[s] = run;
  }
  __syncthreads();
  if (tid < 160) {
    const int base = st[tid], l = ln[tid];
    for (int t = 0; t < l; ++t) rowmap[s * 4800 + base + t] = tid * 30 + t;
  }
}

// ---------------------------------------------------------------------------
// K0: transpose U to fp16 (hi only) via LDS tiles (for k1).
// ---------------------------------------------------------------------------
__global__ __launch_bounds__(256) void k0_usplit(const float* __restrict__ U,
                                                 _Float16* __restrict__ Uh) {
  const int s = blockIdx.z;
  const int k0 = blockIdx.x * 64;
  const int n0 = blockIdx.y * 64;
  const int tid = threadIdx.x;
  __shared__ _Float16 Th[64 * 66];
  const float* Us = U + (size_t)s * 768 * 512;
#pragma unroll
  for (int rep = 0; rep < 16; ++rep) {
    const int idx = rep * 256 + tid;
    const int r = idx >> 6, c = idx & 63;
    Th[r * 66 + c] = (_Float16)Us[(size_t)(k0 + r) * 512 + n0 + c];
  }
  __syncthreads();
  _Float16* uhs = Uh + (size_t)s * 512 * 768;
#pragma unroll
  for (int rep = 0; rep < 8; ++rep) {
    const int idx = rep * 256 + tid;
    const int nn = idx >> 5;
    const int kp = (idx & 31) * 2;
    const f16x2 h2 = {Th[kp * 66 + nn], Th[(kp + 1) * 66 + nn]};
    *(f16x2*)&uhs[(size_t)(n0 + nn) * 768 + k0 + kp] = h2;
  }
}

// ---------------------------------------------------------------------------
// K0w: pack Wall (hi only) and Wd (hi) into MFMA B-fragment-linear layout.
// ---------------------------------------------------------------------------
__global__ __launch_bounds__(256) void k0_wprep(const float* __restrict__ Wall,
                                                const float* __restrict__ Wd,
                                                _Float16* __restrict__ Wfh,
                                                _Float16* __restrict__ Dfh) {
  const int w = blockIdx.x, s = blockIdx.y;
  const int tid = threadIdx.x;
  const float* Ws = Wall + (size_t)s * 65536;
  _Float16* oh = Wfh + (size_t)(s * 8 + w) * 8192;
  for (int c = tid; c < 1024; c += 256) {
    const int kt = c >> 8, nt = (c >> 6) & 3, l = c & 63;
    const int n = nt * 128 + w * 16 + (l & 15);   // gate-major per wave
    const int kb = kt * 32 + ((l >> 4) << 3);
    f16x8 hv;
#pragma unroll
    for (int e = 0; e < 8; ++e) hv[e] = (_Float16)Ws[(size_t)(kb + e) * 512 + n];
    *(f16x8*)&oh[c * 8] = hv;
  }
  {
    const float* Ds = Wd + (size_t)s * 16384;
    _Float16* od = Dfh + (size_t)(s * 8 + w) * 2048;
    const int c = tid;
    const int kt = c >> 6, l = c & 63;
    const int n = w * 16 + (l & 15);
    const int kb = kt * 32 + ((l >> 4) << 3);
    f16x8 hv;
#pragma unroll
    for (int e = 0; e < 8; ++e) hv[e] = (_Float16)Ds[(size_t)(kb + e) * 128 + n];
    *(f16x8*)&od[c * 8] = hv;
  }
}

// ---------------------------------------------------------------------------
// K0a: pack a1_W1 and a1_W2 into per-wave 16-col B-frag layout.
// ---------------------------------------------------------------------------
__global__ __launch_bounds__(256) void k0_aprep(const float* __restrict__ W1,
                                                const float* __restrict__ W2,
                                                _Float16* __restrict__ W1f,
                                                _Float16* __restrict__ W2f) {
  const int w = blockIdx.x, s = blockIdx.y;
  const int c = threadIdx.x;          // 0..255 = kt*64 + l
  const int kt = c >> 6, l = c & 63;
  const int n = w * 16 + (l & 15);
  const int kb = kt * 32 + ((l >> 4) << 3);
  const float* W1s = W1 + (size_t)s * 16384;
  const float* W2s = W2 + (size_t)s * 16384;
  f16x8 v1, v2;
#pragma unroll
  for (int e = 0; e < 8; ++e) {
    v1[e] = (_Float16)W1s[(size_t)(kb + e) * 128 + n];
    v2[e] = (_Float16)W2s[(size_t)(kb + e) * 128 + n];
  }
  *(f16x8*)&W1f[(size_t)(s * 8 + w) * 2048 + c * 8] = v1;
  *(f16x8*)&W2f[(size_t)(s * 8 + w) * 2048 + c * 8] = v2;
}

// ---------------------------------------------------------------------------
// K1 v5: XU = x @ U + bU via MFMA (unchanged from round 14).
// ---------------------------------------------------------------------------
__global__ __launch_bounds__(256, 4) void k1_xu(const float* __restrict__ sent,
                                                const _Float16* __restrict__ Uh,
                                                const float* __restrict__ bU,
                                                const int* __restrict__ rowmap,
                                                const int* __restrict__ Ms,
                                                float* __restrict__ XU) {
  const int s = blockIdx.x;
  const int M = Ms[s];
  const int nt = blockIdx.y & 3;
  const int mt = blockIdx.y >> 2;
  if (mt * 128 >= M) return;
  const int tid = threadIdx.x;
  const int lane = tid & 63, wid = tid >> 6;
  const int wm = wid >> 1, wn = wid & 1;

  __shared__ _Float16 Al[2][128 * 32];
  __shared__ _Float16 Bh[2][128 * 32];

  const int ar1 = tid >> 2;
  const int chk = tid & 3;
  const int afk = chk * 8;
  const int fw = (ar1 ^ (ar1 >> 2)) & 3;
  const int wA1 = ar1 * 32 + ((chk ^ fw) * 8);
  const int wA2 = wA1 + 64 * 32;

  const int* rms = rowmap + s * 4800;
  const float* asrc1;
  const float* asrc2;
  {
    int i1 = mt * 128 + ar1; if (i1 > M - 1) i1 = M - 1;
    const int grow = rms[i1];
    const int nn = grow / 30, tt = grow % 30, ab = nn / 5, ad = nn % 5;
    asrc1 = sent + (size_t)((((ab * 8 + s) * 5 + ad) * 30) + tt) * 768 + afk;
  }
  {
    int i2 = mt * 128 + ar1 + 64; if (i2 > M - 1) i2 = M - 1;
    const int grow = rms[i2];
    const int nn = grow / 30, tt = grow % 30, ab = nn / 5, ad = nn % 5;
    asrc2 = sent + (size_t)((((ab * 8 + s) * 5 + ad) * 30) + tt) * 768 + afk;
  }
  const _Float16* UhS = Uh + (size_t)s * 512 * 768;
  const _Float16* bh1 = UhS + (size_t)(nt * 128 + ar1) * 768 + afk;
  const _Float16* bh2 = UhS + (size_t)(nt * 128 + ar1 + 64) * 768 + afk;

  const int q = lane >> 4;
  const int l15 = lane & 15;
  int aoff[4], boff[4];
#pragma unroll
  for (int f = 0; f < 4; ++f) {
    {
      const int row = wm * 64 + f * 16 + l15;
      const int fr = (row ^ (row >> 2)) & 3;
      aoff[f] = row * 32 + ((q ^ fr) * 8);
    }
    {
      const int row = wn * 64 + f * 16 + l15;
      const int fr = (row ^ (row >> 2)) & 3;
      boff[f] = row * 32 + ((q ^ fr) * 8);
    }
  }

  f32x4 acc[4][4];
#pragma unroll
  for (int i = 0; i < 4; ++i)
#pragma unroll
    for (int j = 0; j < 4; ++j) acc[i][j] = (f32x4){0.f, 0.f, 0.f, 0.f};

  {
    const float4 a1a = *(const float4*)(asrc1);
    const float4 a1b = *(const float4*)(asrc1 + 4);
    const float4 a2a = *(const float4*)(asrc2);
    const float4 a2b = *(const float4*)(asrc2 + 4);
    const f16x8 vh1 = *(const f16x8*)(bh1);
    const f16x8 vh2 = *(const f16x8*)(bh2);
    f16x8 h1, h2;
    h1[0]=(_Float16)a1a.x; h1[1]=(_Float16)a1a.y; h1[2]=(_Float16)a1a.z; h1[3]=(_Float16)a1a.w;
    h1[4]=(_Float16)a1b.x; h1[5]=(_Float16)a1b.y; h1[6]=(_Float16)a1b.z; h1[7]=(_Float16)a1b.w;
    h2[0]=(_Float16)a2a.x; h2[1]=(_Float16)a2a.y; h2[2]=(_Float16)a2a.z; h2[3]=(_Float16)a2a.w;
    h2[4]=(_Float16)a2b.x; h2[5]=(_Float16)a2b.y; h2[6]=(_Float16)a2b.z; h2[7]=(_Float16)a2b.w;
    *(f16x8*)&Al[0][wA1] = h1;
    *(f16x8*)&Al[0][wA2] = h2;
    *(f16x8*)&Bh[0][wA1] = vh1;
    *(f16x8*)&Bh[0][wA2] = vh2;
  }
  __syncthreads();

  int cur = 0;
  for (int ks = 0; ks < 24; ++ks) {
    const int nxt = cur ^ 1;
    const bool more = (ks < 23);
    float4 a1a, a1b, a2a, a2b;
    f16x8 vh1, vh2;
    if (more) {
      const int ko = (ks + 1) * 32;
      a1a = *(const float4*)(asrc1 + ko);
      a1b = *(const float4*)(asrc1 + ko + 4);
      a2a = *(const float4*)(asrc2 + ko);
      a2b = *(const float4*)(asrc2 + ko + 4);
      vh1 = *(const f16x8*)(bh1 + ko);
      vh2 = *(const f16x8*)(bh2 + ko);
    }
    {
      const _Float16* Ab = &Al[cur][0];
      const _Float16* Bhb = &Bh[cur][0];
      f16x8 af[4], bhf[4];
#pragma unroll
      for (int fm = 0; fm < 4; ++fm) af[fm] = *(const f16x8*)&Ab[aoff[fm]];
#pragma unroll
      for (int fn = 0; fn < 4; ++fn) bhf[fn] = *(const f16x8*)&Bhb[boff[fn]];
#pragma unroll
      for (int fm = 0; fm < 4; ++fm)
#pragma unroll
        for (int fn = 0; fn < 4; ++fn)
          acc[fm][fn] = __builtin_amdgcn_mfma_f32_16x16x32_f16(af[fm], bhf[fn], acc[fm][fn], 0, 0, 0);
    }
    if (more) {
      f16x8 h1, h2;
      h1[0]=(_Float16)a1a.x; h1[1]=(_Float16)a1a.y; h1[2]=(_Float16)a1a.z; h1[3]=(_Float16)a1a.w;
      h1[4]=(_Float16)a1b.x; h1[5]=(_Float16)a1b.y; h1[6]=(_Float16)a1b.z; h1[7]=(_Float16)a1b.w;
      h2[0]=(_Float16)a2a.x; h2[1]=(_Float16)a2a.y; h2[2]=(_Float16)a2a.z; h2[3]=(_Float16)a2a.w;
      h2[4]=(_Float16)a2b.x; h2[5]=(_Float16)a2b.y; h2[6]=(_Float16)a2b.z; h2[7]=(_Float16)a2b.w;
      *(f16x8*)&Al[nxt][wA1] = h1;
      *(f16x8*)&Al[nxt][wA2] = h2;
      *(f16x8*)&Bh[nxt][wA1] = vh1;
      *(f16x8*)&Bh[nxt][wA2] = vh2;
    }
    barrier_lds_only();
    cur = nxt;
  }

  const int lq = lane >> 4;
  const int colbase = nt * 128 + wn * 64;
  const int ibase = mt * 128 + wm * 64;
  float* XUs = XU + (size_t)s * 4800 * 512;
  int rowm[4][4];
#pragma unroll
  for (int fm = 0; fm < 4; ++fm)
#pragma unroll
    for (int r = 0; r < 4; ++r) {
      const int i = ibase + fm * 16 + lq * 4 + r;
      rowm[fm][r] = (i < M) ? rms[i] : -1;
    }
#pragma unroll
  for (int fn = 0; fn < 4; ++fn) {
    const int col = colbase + fn * 16 + l15;
    const float bias = bU[s * 512 + col];
#pragma unroll
    for (int fm = 0; fm < 4; ++fm)
#pragma unroll
      for (int r = 0; r < 4; ++r) {
        const int row = rowm[fm][r];
        if (row >= 0) XUs[(size_t)row * 512 + col] = acc[fm][fn][r] + bias;
      }
  }
}

// ---------------------------------------------------------------------------
// K2 v10: TWO independent 16-seq recurrences interleaved per block.
//   40 blocks = (s, 5 group-pairs), 512 thr. Groups A/B share the same
//   register-stationary weights; per step M(A);M(B);E(A);E(B) so group B's
//   MFMAs and loads overlap group A's latency. XU read direct from global
//   at step top (round-8 A/B: LDS staging of XU was neutral). One LDS-only
//   barrier per step covers both groups' state double-buffers.
// ---------------------------------------------------------------------------
__global__ __launch_bounds__(512, 2) void k2_tlstm(const _Float16* __restrict__ Wfh,
                                                   const _Float16* __restrict__ Dfh,
                                                   const float* __restrict__ ball,
                                                   const float* __restrict__ bd,
                                                   const float* __restrict__ XU,
                                                   const float* __restrict__ times,
                                                   const int* __restrict__ lens,
                                                   float* __restrict__ outs,
                                                   float* __restrict__ hn) {
  const int s = blockIdx.x;
  const int pg = blockIdx.y;                 // group pair 0..4
  const int tid = threadIdx.x;
  const int w = tid >> 6, l = tid & 63;

  __shared__ _Float16 hhb[2][2][2048];       // [group][buf]
  __shared__ _Float16 chb[2][2][2048];
  __shared__ float tsh[2][16 * 32];
  __shared__ int lensh[2][16];

  if (tid < 32) {
    const int gi = tid >> 4, r = tid & 15;
    const int n = (pg * 2 + gi) * 16 + r;
    lensh[gi][r] = lens[((n / 5) * 8 + s) * 5 + (n % 5)];
  }
  for (int idx = tid; idx < 960; idx += 512) {
    const int gi = idx / 480;
    const int rr = (idx % 480) / 30, cc = idx % 30;
    const int n = (pg * 2 + gi) * 16 + rr;
    tsh[gi][rr * 32 + cc] = times[(((n / 5) * 8 + s) * 5 + (n % 5)) * 30 + cc];
  }

  // ---- register-stationary weight fragments (shared by both groups) ----
  f16x8 Bh[16], Dh[4];
  {
    const _Float16* wb = Wfh + (size_t)(s * 8 + w) * 8192 + l * 8;
    const _Float16* db = Dfh + (size_t)(s * 8 + w) * 2048 + l * 8;
#pragma unroll
    for (int c = 0; c < 16; ++c) Bh[c] = *(const f16x8*)&wb[c * 512];
#pragma unroll
    for (int c = 0; c < 4; ++c) Dh[c] = *(const f16x8*)&db[c * 512];
  }

  const int hd = w * 16 + (l & 15);
  const int rq0 = (l >> 4) * 4;
  const int lp0 = rq0 | (((hd >> 3) & 3) << 4);
  const int eoff0 = ((hd >> 5) * 64 + lp0) * 8 + (hd & 7);

#pragma unroll
  for (int gi = 0; gi < 2; ++gi)
#pragma unroll
    for (int qq = 0; qq < 4; ++qq) {
      hhb[gi][0][eoff0 + qq * 8] = (_Float16)0.f;
      chb[gi][0][eoff0 + qq * 8] = (_Float16)0.f;
    }

  int n_q[2][4];
  size_t xub[2][4];
#pragma unroll
  for (int gi = 0; gi < 2; ++gi)
#pragma unroll
    for (int qq = 0; qq < 4; ++qq) {
      n_q[gi][qq] = (pg * 2 + gi) * 16 + rq0 + qq;
      xub[gi][qq] = ((size_t)(s * 160 + n_q[gi][qq])) * 30 * 512 + hd;
    }
  float blr[4];
#pragma unroll
  for (int g = 0; g < 4; ++g) blr[g] = ball[s * 512 + g * 128 + hd];
  const float bdj = bd[s * 128 + hd];

  __syncthreads();

  int len_q[2][4];
  int maxlen = 0;
#pragma unroll
  for (int gi = 0; gi < 2; ++gi)
#pragma unroll
    for (int i = 0; i < 16; ++i) maxlen = max(maxlen, lensh[gi][i]);
#pragma unroll
  for (int gi = 0; gi < 2; ++gi)
#pragma unroll
    for (int qq = 0; qq < 4; ++qq) len_q[gi][qq] = lensh[gi][rq0 + qq];

  float creg[2][4] = {};
  float hreg[2][4] = {};
  float oprev[2][4] = {};

  for (int t = 0; t < maxlen; ++t) {
    const int p = t & 1;

    // deferred global stores for step t-1, both groups (fly across barrier)
    if (t > 0) {
      const int tp = t - 1;
#pragma unroll
      for (int gi = 0; gi < 2; ++gi)
#pragma unroll
        for (int qq = 0; qq < 4; ++qq) {
          if (tp < len_q[gi][qq]) {
            outs[((size_t)(s * 160 + n_q[gi][qq]) * 30 + tp) * 128 + hd] = oprev[gi][qq];
            if (tp == len_q[gi][qq] - 1)
              hn[(size_t)(s * 160 + n_q[gi][qq]) * 128 + hd] = oprev[gi][qq];
          }
        }
    }

    // XU loads for step t, both groups (issued before M; consumed in E)
    float xg[2][4][4];
#pragma unroll
    for (int gi = 0; gi < 2; ++gi)
#pragma unroll
      for (int qq = 0; qq < 4; ++qq) {
        const float* xp = XU + xub[gi][qq] + (size_t)t * 512;
#pragma unroll
        for (int g = 0; g < 4; ++g) xg[gi][qq][g] = xp[g * 128];
      }

    // ---- M phase: group A then group B (independent chains) ----
    f32x4 amA[2][4], amB[2][4], dm[2];
#pragma unroll
    for (int gi = 0; gi < 2; ++gi) {
#pragma unroll
      for (int g = 0; g < 4; ++g) {
        amA[gi][g] = (f32x4){0.f, 0.f, 0.f, 0.f};
        amB[gi][g] = (f32x4){0.f, 0.f, 0.f, 0.f};
      }
      dm[gi] = (f32x4){0.f, 0.f, 0.f, 0.f};
#pragma unroll
      for (int kt = 0; kt < 2; ++kt) {
        const f16x8 ah0 = *(const f16x8*)&hhb[gi][p][(kt * 64 + l) * 8];
        const f16x8 ah1 = *(const f16x8*)&hhb[gi][p][((kt + 2) * 64 + l) * 8];
        const f16x8 cf0 = *(const f16x8*)&chb[gi][p][(kt * 64 + l) * 8];
        const f16x8 cf1 = *(const f16x8*)&chb[gi][p][((kt + 2) * 64 + l) * 8];
#pragma unroll
        for (int g = 0; g < 4; ++g) {
          amA[gi][g] = __builtin_amdgcn_mfma_f32_16x16x32_f16(ah0, Bh[kt * 4 + g], amA[gi][g], 0, 0, 0);
          amB[gi][g] = __builtin_amdgcn_mfma_f32_16x16x32_f16(ah1, Bh[(kt + 2) * 4 + g], amB[gi][g], 0, 0, 0);
        }
        dm[gi] = __builtin_amdgcn_mfma_f32_16x16x32_f16(cf0, Dh[kt], dm[gi], 0, 0, 0);
        dm[gi] = __builtin_amdgcn_mfma_f32_16x16x32_f16(cf1, Dh[kt + 2], dm[gi], 0, 0, 0);
      }
    }

    // ---- E phase: both groups; state writes to buf p^1 ----
#pragma unroll
    for (int gi = 0; gi < 2; ++gi) {
#pragma unroll
      for (int qq = 0; qq < 4; ++qq) {
        if (t < len_q[gi][qq]) {
          const float tt = tsh[gi][(rq0 + qq) * 32 + t];
          const float cs1 = tanhf_(dm[gi][qq] + bdj);
          const float f  = sigf(amA[gi][0][qq] + amB[gi][0][qq] + xg[gi][qq][0] + blr[0]);
          const float ii = sigf(amA[gi][1][qq] + amB[gi][1][qq] + xg[gi][qq][1] + blr[1]);
          const float o  = sigf(amA[gi][2][qq] + amB[gi][2][qq] + xg[gi][qq][2] + blr[2]);
          const float ct = sigf(amA[gi][3][qq] + amB[gi][3][qq] + xg[gi][qq][3] + blr[3]);
          const float c2 = f * (creg[gi][qq] + cs1 * (tt - 1.f)) + ii * ct;
          creg[gi][qq] = c2;
          hreg[gi][qq] = o * tanhf_(c2);
          oprev[gi][qq] = o;
        }
        hhb[gi][p ^ 1][eoff0 + qq * 8] = (_Float16)hreg[gi][qq];
        chb[gi][p ^ 1][eoff0 + qq * 8] = (_Float16)creg[gi][qq];
      }
    }

    barrier_lds_only();
  }

  {
    const int tp = maxlen - 1;
#pragma unroll
    for (int gi = 0; gi < 2; ++gi)
#pragma unroll
      for (int qq = 0; qq < 4; ++qq) {
        if (tp >= 0 && tp < len_q[gi][qq]) {
          outs[((size_t)(s * 160 + n_q[gi][qq]) * 30 + tp) * 128 + hd] = oprev[gi][qq];
          if (tp == len_q[gi][qq] - 1)
            hn[(size_t)(s * 160 + n_q[gi][qq]) * 128 + hd] = oprev[gi][qq];
        }
      }
  }
}

// ---------------------------------------------------------------------------
// K3 v7: MFMA attention-1 with LDS-staged o-tile (unchanged).
// ---------------------------------------------------------------------------
__global__ __launch_bounds__(512, 2) void k3_attn1(const _Float16* __restrict__ W1f,
                                                   const _Float16* __restrict__ W2f,
                                                   const float* __restrict__ b1,
                                                   const float* __restrict__ b2,
                                                   const float* __restrict__ V,
                                                   const float* __restrict__ outs,
                                                   const float* __restrict__ hn,
                                                   const int* __restrict__ lens,
                                                   float* __restrict__ ctx) {
  const int s = blockIdx.x;
  const int sg = blockIdx.y;
  const int tid = threadIdx.x;
  const int w = tid >> 6, l = tid & 63;
  const int nbase = s * 160 + sg * 8;

  __shared__ _Float16 osh[32768];
  __shared__ float u[16][132];
  __shared__ float red[8][8][32];
  __shared__ float score[8][32];
  __shared__ int lensh[8];

  if (tid < 8) {
    const int n = sg * 8 + tid;
    lensh[tid] = lens[((n / 5) * 8 + s) * 5 + (n % 5)];
  }

#pragma unroll
  for (int i = 0; i < 8; ++i) {
    const int c = tid + i * 512;
    const int nl = c >> 9;
    const int th = (c >> 8) & 1;
    const int kt = (c >> 6) & 3;
    const int lp = c & 63;
    const int t15 = lp & 15;
    const int kb = kt * 32 + (lp >> 4) * 8;
    const int t = th * 16 + t15;
    f16x8 v;
    if (t < 30) {
      const float* src = outs + ((size_t)(nbase + nl) * 30 + t) * 128 + kb;
      const float4 a = *(const float4*)(src);
      const float4 b = *(const float4*)(src + 4);
      v[0]=(_Float16)a.x; v[1]=(_Float16)a.y; v[2]=(_Float16)a.z; v[3]=(_Float16)a.w;
      v[4]=(_Float16)b.x; v[5]=(_Float16)b.y; v[6]=(_Float16)b.z; v[7]=(_Float16)b.w;
    } else {
      v = (f16x8){(_Float16)0.f,(_Float16)0.f,(_Float16)0.f,(_Float16)0.f,
                  (_Float16)0.f,(_Float16)0.f,(_Float16)0.f,(_Float16)0.f};
    }
    *(f16x8*)&osh[c * 8] = v;
  }

  f16x8 W1r[4], W2r[4];
  {
    const _Float16* w1b = W1f + (size_t)(s * 8 + w) * 2048 + l * 8;
    const _Float16* w2b = W2f + (size_t)(s * 8 + w) * 2048 + l * 8;
#pragma unroll
    for (int kt = 0; kt < 4; ++kt) {
      W1r[kt] = *(const f16x8*)&w1b[kt * 512];
      W2r[kt] = *(const f16x8*)&w2b[kt * 512];
    }
  }

  const int hd = w * 16 + (l & 15);
  const float Vhd = V[s * 128 + hd];
  const float b12 = b1[s * 128 + hd] + b2[s * 128 + hd];
  const int kc = (l >> 4) << 3;

  {
    const int rsrc = min(l & 15, 7);
    f32x4 dm = (f32x4){0.f, 0.f, 0.f, 0.f};
#pragma unroll
    for (int kt = 0; kt < 4; ++kt) {
      const float* hp = hn + (size_t)(nbase + rsrc) * 128 + kt * 32 + kc;
      const float4 a = *(const float4*)(hp);
      const float4 b = *(const float4*)(hp + 4);
      f16x8 ah;
      ah[0]=(_Float16)a.x; ah[1]=(_Float16)a.y; ah[2]=(_Float16)a.z; ah[3]=(_Float16)a.w;
      ah[4]=(_Float16)b.x; ah[5]=(_Float16)b.y; ah[6]=(_Float16)b.z; ah[7]=(_Float16)b.w;
      dm = __builtin_amdgcn_mfma_f32_16x16x32_f16(ah, W1r[kt], dm, 0, 0, 0);
    }
#pragma unroll
    for (int q = 0; q < 4; ++q) u[(l >> 4) * 4 + q][hd] = dm[q] + b12;
  }
  __syncthreads();

#pragma unroll
  for (int m = 0; m < 16; ++m) {
    const int nl = m >> 1, th = m & 1;
    const int cbase = ((nl * 2 + th) * 4) * 64;
    f32x4 acc = (f32x4){0.f, 0.f, 0.f, 0.f};
#pragma unroll
    for (int kt = 0; kt < 4; ++kt) {
      const f16x8 ah = *(const f16x8*)&osh[(cbase + kt * 64 + l) * 8];
      acc = __builtin_amdgcn_mfma_f32_16x16x32_f16(ah, W2r[kt], acc, 0, 0, 0);
    }
    const float uv = u[nl][hd];
#pragma unroll
    for (int q = 0; q < 4; ++q) {
      float p = tanhf_(acc[q] + uv) * Vhd;
      p += __shfl_xor(p, 1);
      p += __shfl_xor(p, 2);
      p += __shfl_xor(p, 4);
      p += __shfl_xor(p, 8);
      const int t = th * 16 + (l >> 4) * 4 + q;
      if ((l & 15) == 0 && t < 30) red[w][nl][t] = p;
    }
  }
  __syncthreads();

  if (tid < 256) {
    const int nl = tid >> 5, t = tid & 31;
    if (t < 30) {
      float sc = 0.f;
#pragma unroll
      for (int ww = 0; ww < 8; ++ww) sc += red[ww][nl][t];
      score[nl][t] = sc;
    }
  }
  __syncthreads();

  {
    const int nl = tid >> 6, jg = tid & 63;
    const int len = lensh[nl];
    float mx = -1e30f;
    for (int t = 0; t < len; ++t) mx = fmaxf(mx, score[nl][t]);
    const float* ob = outs + (size_t)(nbase + nl) * 30 * 128 + jg * 2;
    float sum = 0.f;
    float cx0 = 0.f, cx1 = 0.f;
    for (int t = 0; t < len; ++t) {
      const float e = __expf(score[nl][t] - mx);
      sum += e;
      const float2 o2 = *(const float2*)(ob + (size_t)t * 128);
      cx0 += e * o2.x; cx1 += e * o2.y;
    }
    const float r = rcp_(sum);
    float2 res = {cx0 * r, cx1 * r};
    *(float2*)&ctx[(size_t)(nbase + nl) * 128 + jg * 2] = res;
  }
}

// ---------------------------------------------------------------------------
// K4: LSTM over D=5 (unchanged).
// ---------------------------------------------------------------------------
__global__ __launch_bounds__(512, 2) void k4_lstm2(const float* __restrict__ Wih,
                                                   const float* __restrict__ bih,
                                                   const float* __restrict__ Whh,
                                                   const float* __restrict__ bhh,
                                                   const float* __restrict__ ctx,
                                                   float* __restrict__ hsout,
                                                   float* __restrict__ hlast) {
  const int s = blockIdx.y, b = blockIdx.x;
  const int gj = threadIdx.x;
  __shared__ float xs[5][128];
  __shared__ float hsm[128];
  __shared__ float gsh[512];

  for (int idx = gj; idx < 640; idx += 512)
    (&xs[0][0])[idx] = ctx[(size_t)(s * 160 + b * 5) * 128 + idx];
  if (gj < 128) hsm[gj] = 0.f;
  __syncthreads();

  const float* Wis = Wih + (size_t)s * 65536;
  const float* Whs = Whh + (size_t)s * 65536;
  const float bias = bih[s * 512 + gj] + bhh[s * 512 + gj];
  float xw[5] = {bias, bias, bias, bias, bias};
  float whh[128];
#pragma unroll
  for (int k = 0; k < 128; ++k) {
    const float wi = Wis[k * 512 + gj];
    whh[k] = Whs[k * 512 + gj];
#pragma unroll
    for (int dd = 0; dd < 5; ++dd) xw[dd] += xs[dd][k] * wi;
  }

  float c = 0.f;
  for (int dd = 0; dd < 5; ++dd) {
    float g = xw[dd];
#pragma unroll
    for (int k = 0; k < 128; ++k) g += hsm[k] * whh[k];
    gsh[gj] = g;
    __syncthreads();
    if (gj < 128) {
      const int j = gj;
      const float c2 = sigf(gsh[128 + j]) * c + sigf(gsh[j]) * tanhf_(gsh[256 + j]);
      const float h2 = sigf(gsh[384 + j]) * tanhf_(c2);
      c = c2;
      hsm[j] = h2;
      hsout[((size_t)(s * 32 + b) * 5 + dd) * 128 + j] = h2;
      if (dd == 4) hlast[(size_t)(s * 32 + b) * 128 + j] = h2;
    }
    __syncthreads();
  }
}

// ---------------------------------------------------------------------------
// K5: attention 2 + output MLP (unchanged).
// ---------------------------------------------------------------------------
__global__ __launch_bounds__(128) void k5_attn2(const float* __restrict__ W1,
                                                const float* __restrict__ b1,
                                                const float* __restrict__ W2,
                                                const float* __restrict__ b2,
                                                const float* __restrict__ V,
                                                const float* __restrict__ bV,
                                                const float* __restrict__ x1W,
                                                const float* __restrict__ x1b,
                                                const float* __restrict__ x2W,
                                                const float* __restrict__ x2b,
                                                const float* __restrict__ hs,
                                                const float* __restrict__ hlast,
                                                float* __restrict__ y) {
  const int s = blockIdx.y, b = blockIdx.x, j = threadIdx.x;
  __shared__ float hl[128], hsm[5][128], t1[128], cs2[128], sc[5], red[2];
  hl[j] = hlast[(size_t)(s * 32 + b) * 128 + j];
  const float* hsrc = hs + (size_t)(s * 32 + b) * 640;
  for (int idx = j; idx < 640; idx += 128) (&hsm[0][0])[idx] = hsrc[idx];
  __syncthreads();

  const float* W1s = W1 + (size_t)s * 16384;
  const float* W2s = W2 + (size_t)s * 16384;
  float u = b1[s * 128 + j] + b2[s * 128 + j];
  for (int k = 0; k < 128; ++k) u += hl[k] * W1s[k * 128 + j];
  const float Vj = V[s * 128 + j];
  const int lane = j & 63, wid = j >> 6;

  for (int d = 0; d < 5; ++d) {
    float a = u;
    for (int k = 0; k < 128; ++k) a += hsm[d][k] * W2s[k * 128 + j];
    float p = tanhf_(a) * Vj;
#pragma unroll
    for (int off = 32; off; off >>= 1) p += __shfl_down(p, off);
    if (lane == 0) red[wid] = p;
    __syncthreads();
    if (j == 0) sc[d] = red[0] + red[1] + bV[s];
    __syncthreads();
  }

  float m = -1e30f;
  for (int d = 0; d < 5; ++d) m = fmaxf(m, sc[d]);
  float sum = 0.f;
  for (int d = 0; d < 5; ++d) sum += __expf(sc[d] - m);
  float cx = 0.f;
  for (int d = 0; d < 5; ++d) cx += __expf(sc[d] - m) * hsm[d][j];
  cs2[j] = cx / sum;
  __syncthreads();

  float a = x1b[s * 128 + j];
  for (int k = 0; k < 128; ++k) a += cs2[k] * x1W[(size_t)s * 16384 + k * 128 + j];
  t1[j] = fmaxf(a, 0.f);
  __syncthreads();

  if (j < 64) {
    float yy = x2b[s * 64 + j];
    for (int k = 0; k < 128; ++k) yy += t1[k] * x2W[(size_t)(s * 128 + k) * 64 + j];
    y[(size_t)(s * 32 + b) * 64 + j] = yy;
  }
}

// ---------------------------------------------------------------------------
// K6: final combine (unchanged).
// ---------------------------------------------------------------------------
__global__ __launch_bounds__(256) void k6_final(const float* __restrict__ stock,
                                                const float* __restrict__ h1W,
                                                const float* __restrict__ h1b,
                                                const float* __restrict__ h2W,
                                                const float* __restrict__ h2b,
                                                const float* __restrict__ hcW,
                                                const float* __restrict__ hcb,
                                                const float* __restrict__ yws,
                                                float* __restrict__ out) {
  const int tid = threadIdx.x;
  __shared__ float sf[32 * 17];
  __shared__ float hid[32 * 64];
  __shared__ float xs[32 * 32];
  for (int idx = tid; idx < 544; idx += 256) sf[idx] = stock[idx];
  __syncthreads();
  for (int idx = tid; idx < 2048; idx += 256) {
    const int b = idx >> 6, k = idx & 63;
    float a = h1b[k];
    for (int q = 0; q < 17; ++q) a += sf[b * 17 + q] * h1W[q * 64 + k];
    hid[idx] = fmaxf(a, 0.f);
  }
  __syncthreads();
  for (int idx = tid; idx < 1024; idx += 256) {
    const int b = idx >> 5, mm = idx & 31;
    float a = h2b[mm];
    for (int k = 0; k < 64; ++k) a += hid[b * 64 + k] * h2W[k * 32 + mm];
    xs[idx] = a;
  }
  __syncthreads();
  {
    const int b = tid >> 3, o = tid & 7;
    float a = hcb[o];
    for (int c = 0; c < 32; ++c) a += xs[b * 32 + c] * hcW[c * 8 + o];
    for (int c = 32; c < 544; ++c) {
      const int ss = (c - 32) >> 6, k = (c - 32) & 63;
      a += yws[((size_t)ss * 32 + b) * 64 + k] * hcW[c * 8 + o];
    }
    out[tid] = tanhf_(a);
  }
}

// ---------------------------------------------------------------------------
extern "C" void kernel_launch(void* const* d_in, const int* in_sizes, int n_in,
                              void* d_out, int out_size, void* d_ws, size_t ws_size,
                              hipStream_t stream) {
  (void)in_sizes; (void)n_in; (void)out_size; (void)ws_size;
  const float* stock = (const float*)d_in[0];
  const float* sent  = (const float*)d_in[1];
  const float* times = (const float*)d_in[2];
  const int*   lens  = (const int*)d_in[3];
  const float* tlWall = (const float*)d_in[4];
  const float* tlball = (const float*)d_in[5];
  const float* tlUall = (const float*)d_in[6];
  const float* tlbU   = (const float*)d_in[7];
  const float* tlWd   = (const float*)d_in[8];
  const float* tlbd   = (const float*)d_in[9];
  const float* a1W1 = (const float*)d_in[10];
  const float* a1b1 = (const float*)d_in[11];
  const float* a1W2 = (const float*)d_in[12];
  const float* a1b2 = (const float*)d_in[13];
  const float* a1V  = (const float*)d_in[14];
  const float* a1bV = (const float*)d_in[15];
  const float* l2Wih = (const float*)d_in[16];
  const float* l2bih = (const float*)d_in[17];
  const float* l2Whh = (const float*)d_in[18];
  const float* l2bhh = (const float*)d_in[19];
  const float* a2W1 = (const float*)d_in[20];
  const float* a2b1 = (const float*)d_in[21];
  const float* a2W2 = (const float*)d_in[22];
  const float* a2b2 = (const float*)d_in[23];
  const float* a2V  = (const float*)d_in[24];
  const float* a2bV = (const float*)d_in[25];
  const float* x1W  = (const float*)d_in[26];
  const float* x1b  = (const float*)d_in[27];
  const float* x2W  = (const float*)d_in[28];
  const float* x2b  = (const float*)d_in[29];
  const float* h1W  = (const float*)d_in[30];
  const float* h1b  = (const float*)d_in[31];
  const float* h2W  = (const float*)d_in[32];
  const float* h2b  = (const float*)d_in[33];
  const float* hcW  = (const float*)d_in[34];
  const float* hcb  = (const float*)d_in[35];

  float* ws = (float*)d_ws;
  float* XU    = ws;               // 8*160*30*512   = 19,660,800
  float* outs  = XU + 19660800;    // 8*160*30*128   =  4,915,200
  float* hnb   = outs + 4915200;   // 8*160*128      =    163,840
  float* ctx   = hnb + 163840;     // 8*160*128      =    163,840
  float* hsb   = ctx + 163840;     // 8*32*5*128     =    163,840
  float* hlast = hsb + 163840;     // 8*32*128       =     32,768
  float* yb    = hlast + 32768;    // 8*32*64        =     16,384
  _Float16* Uhw = (_Float16*)(yb + 16384);    // 8*512*768 halfs
  _Float16* Wfh = Uhw + 8 * 512 * 768;        // 8*8*8192 halfs
  _Float16* Dfh = Wfh + 8 * 8 * 8192;         // 8*8*2048 halfs
  _Float16* W1f = Dfh + 8 * 8 * 2048;         // 8*8*2048 halfs
  _Float16* W2f = W1f + 8 * 8 * 2048;         // 8*8*2048 halfs
  int* rowmap = (int*)(W2f + 8 * 8 * 2048);   // 8*4800 ints
  int* Msd    = rowmap + 8 * 4800;            // 8 ints

  k0_rowmap<<<8, 256, 0, stream>>>(lens, rowmap, Msd);
  k0_usplit<<<dim3(12, 8, 8), 256, 0, stream>>>(tlUall, Uhw);
  k0_wprep<<<dim3(8, 8), 256, 0, stream>>>(tlWall, tlWd, Wfh, Dfh);
  k0_aprep<<<dim3(8, 8), 256, 0, stream>>>(a1W1, a1W2, W1f, W2f);
  k1_xu<<<dim3(8, 152), 256, 0, stream>>>(sent, Uhw, tlbU, rowmap, Msd, XU);
  k2_tlstm<<<dim3(8, 5), 512, 0, stream>>>(Wfh, Dfh, tlball, tlbd, XU, times, lens, outs, hnb);
  k3_attn1<<<dim3(8, 20), 512, 0, stream>>>(W1f, W2f, a1b1, a1b2, a1V, outs, hnb, lens, ctx);
  k4_lstm2<<<dim3(32, 8), 512, 0, stream>>>(l2Wih, l2bih, l2Whh, l2bhh, ctx, hsb, hlast);
  k5_attn2<<<dim3(32, 8), 128, 0, stream>>>(a2W1, a2b1, a2W2, a2b2, a2V, a2bV, x1W, x1b, x2W, x2b, hsb, hlast, yb);
  k6_final<<<1, 256, 0, stream>>>(stock, h1W, h1b, h2W, h2b, hcW, hcb, yb, (float*)d_out);
}

// Round 16
// 215.918 us; speedup vs baseline: 1.2307x; 1.2307x over previous
//
#include <hip/hip_runtime.h>
#include <cstddef>

// Problem constants: S=8, B=32, D=5, T=30, E=768, H=128, 4H=512.

typedef __attribute__((ext_vector_type(8))) _Float16 f16x8;
typedef __attribute__((ext_vector_type(4))) _Float16 f16x4;
typedef __attribute__((ext_vector_type(2))) _Float16 f16x2;
typedef __attribute__((ext_vector_type(4))) float f32x4;

__device__ __forceinline__ float rcp_(float x) { return __builtin_amdgcn_rcpf(x); }
__device__ __forceinline__ float sigf(float x) { return rcp_(1.0f + __expf(-x)); }
__device__ __forceinline__ float tanhf_(float x) { return 1.0f - 2.0f * rcp_(__expf(2.0f * x) + 1.0f); }

// LDS-only barrier: drains lgkmcnt but NOT vmcnt (global ops stay in flight).
__device__ __forceinline__ void barrier_lds_only() {
  asm volatile("s_waitcnt lgkmcnt(0)" ::: "memory");
  __builtin_amdgcn_s_barrier();
  __builtin_amdgcn_sched_barrier(0);
}

// ---------------------------------------------------------------------------
// K0r: per-stock compacted row map: rows (n,t) with t < len[s,n].
// ---------------------------------------------------------------------------
__global__ __launch_bounds__(256) void k0_rowmap(const int* __restrict__ lens,
                                                 int* __restrict__ rowmap,
                                                 int* __restrict__ Ms) {
  const int s = blockIdx.x;
  const int tid = threadIdx.x;
  __shared__ int st[160];
  __shared__ int ln[160];
  if (tid < 160) {
    const int b = tid / 5, d = tid % 5;
    ln[tid] = lens[(b * 8 + s) * 5 + d];
  }
  __syncthreads();
  if (tid == 0) {
    int run = 0;
    for (int n = 0; n < 160; ++n) { st[n] = run; run += ln[n]; }
    Ms[s] = run;
  }
  __syncthreads();
  if (tid < 160) {
    const int base = st[tid], l = ln[tid];
    for (int t = 0; t < l; ++t) rowmap[s * 4800 + base + t] = tid * 30 + t;
  }
}

// ---------------------------------------------------------------------------
// K0: transpose U to fp16 (hi only) via LDS tiles (for k1).
// ---------------------------------------------------------------------------
__global__ __launch_bounds__(256) void k0_usplit(const float* __restrict__ U,
                                                 _Float16* __restrict__ Uh) {
  const int s = blockIdx.z;
  const int k0 = blockIdx.x * 64;
  const int n0 = blockIdx.y * 64;
  const int tid = threadIdx.x;
  __shared__ _Float16 Th[64 * 66];
  const float* Us = U + (size_t)s * 768 * 512;
#pragma unroll
  for (int rep = 0; rep < 16; ++rep) {
    const int idx = rep * 256 + tid;
    const int r = idx >> 6, c = idx & 63;
    Th[r * 66 + c] = (_Float16)Us[(size_t)(k0 + r) * 512 + n0 + c];
  }
  __syncthreads();
  _Float16* uhs = Uh + (size_t)s * 512 * 768;
#pragma unroll
  for (int rep = 0; rep < 8; ++rep) {
    const int idx = rep * 256 + tid;
    const int nn = idx >> 5;
    const int kp = (idx & 31) * 2;
    const f16x2 h2 = {Th[kp * 66 + nn], Th[(kp + 1) * 66 + nn]};
    *(f16x2*)&uhs[(size_t)(n0 + nn) * 768 + k0 + kp] = h2;
  }
}

// ---------------------------------------------------------------------------
// K0w: pack Wall (hi only) and Wd (hi) into MFMA B-fragment-linear layout.
// ---------------------------------------------------------------------------
__global__ __launch_bounds__(256) void k0_wprep(const float* __restrict__ Wall,
                                                const float* __restrict__ Wd,
                                                _Float16* __restrict__ Wfh,
                                                _Float16* __restrict__ Dfh) {
  const int w = blockIdx.x, s = blockIdx.y;
  const int tid = threadIdx.x;
  const float* Ws = Wall + (size_t)s * 65536;
  _Float16* oh = Wfh + (size_t)(s * 8 + w) * 8192;
  for (int c = tid; c < 1024; c += 256) {
    const int kt = c >> 8, nt = (c >> 6) & 3, l = c & 63;
    const int n = nt * 128 + w * 16 + (l & 15);   // gate-major per wave
    const int kb = kt * 32 + ((l >> 4) << 3);
    f16x8 hv;
#pragma unroll
    for (int e = 0; e < 8; ++e) hv[e] = (_Float16)Ws[(size_t)(kb + e) * 512 + n];
    *(f16x8*)&oh[c * 8] = hv;
  }
  {
    const float* Ds = Wd + (size_t)s * 16384;
    _Float16* od = Dfh + (size_t)(s * 8 + w) * 2048;
    const int c = tid;
    const int kt = c >> 6, l = c & 63;
    const int n = w * 16 + (l & 15);
    const int kb = kt * 32 + ((l >> 4) << 3);
    f16x8 hv;
#pragma unroll
    for (int e = 0; e < 8; ++e) hv[e] = (_Float16)Ds[(size_t)(kb + e) * 128 + n];
    *(f16x8*)&od[c * 8] = hv;
  }
}

// ---------------------------------------------------------------------------
// K0a: pack a1_W1 and a1_W2 into per-wave 16-col B-frag layout.
// ---------------------------------------------------------------------------
__global__ __launch_bounds__(256) void k0_aprep(const float* __restrict__ W1,
                                                const float* __restrict__ W2,
                                                _Float16* __restrict__ W1f,
                                                _Float16* __restrict__ W2f) {
  const int w = blockIdx.x, s = blockIdx.y;
  const int c = threadIdx.x;          // 0..255 = kt*64 + l
  const int kt = c >> 6, l = c & 63;
  const int n = w * 16 + (l & 15);
  const int kb = kt * 32 + ((l >> 4) << 3);
  const float* W1s = W1 + (size_t)s * 16384;
  const float* W2s = W2 + (size_t)s * 16384;
  f16x8 v1, v2;
#pragma unroll
  for (int e = 0; e < 8; ++e) {
    v1[e] = (_Float16)W1s[(size_t)(kb + e) * 128 + n];
    v2[e] = (_Float16)W2s[(size_t)(kb + e) * 128 + n];
  }
  *(f16x8*)&W1f[(size_t)(s * 8 + w) * 2048 + c * 8] = v1;
  *(f16x8*)&W2f[(size_t)(s * 8 + w) * 2048 + c * 8] = v2;
}

// ---------------------------------------------------------------------------
// K1 v5: XU = x @ U + bU via MFMA, single fp16 product, XCD-pinned grid,
//   LDS-only K-loop barrier (round-14 state).
// ---------------------------------------------------------------------------
__global__ __launch_bounds__(256, 4) void k1_xu(const float* __restrict__ sent,
                                                const _Float16* __restrict__ Uh,
                                                const float* __restrict__ bU,
                                                const int* __restrict__ rowmap,
                                                const int* __restrict__ Ms,
                                                float* __restrict__ XU) {
  const int s = blockIdx.x;
  const int M = Ms[s];
  const int nt = blockIdx.y & 3;
  const int mt = blockIdx.y >> 2;
  if (mt * 128 >= M) return;
  const int tid = threadIdx.x;
  const int lane = tid & 63, wid = tid >> 6;
  const int wm = wid >> 1, wn = wid & 1;

  __shared__ _Float16 Al[2][128 * 32];
  __shared__ _Float16 Bh[2][128 * 32];

  const int ar1 = tid >> 2;
  const int chk = tid & 3;
  const int afk = chk * 8;
  const int fw = (ar1 ^ (ar1 >> 2)) & 3;
  const int wA1 = ar1 * 32 + ((chk ^ fw) * 8);
  const int wA2 = wA1 + 64 * 32;

  const int* rms = rowmap + s * 4800;
  const float* asrc1;
  const float* asrc2;
  {
    int i1 = mt * 128 + ar1; if (i1 > M - 1) i1 = M - 1;
    const int grow = rms[i1];
    const int nn = grow / 30, tt = grow % 30, ab = nn / 5, ad = nn % 5;
    asrc1 = sent + (size_t)((((ab * 8 + s) * 5 + ad) * 30) + tt) * 768 + afk;
  }
  {
    int i2 = mt * 128 + ar1 + 64; if (i2 > M - 1) i2 = M - 1;
    const int grow = rms[i2];
    const int nn = grow / 30, tt = grow % 30, ab = nn / 5, ad = nn % 5;
    asrc2 = sent + (size_t)((((ab * 8 + s) * 5 + ad) * 30) + tt) * 768 + afk;
  }
  const _Float16* UhS = Uh + (size_t)s * 512 * 768;
  const _Float16* bh1 = UhS + (size_t)(nt * 128 + ar1) * 768 + afk;
  const _Float16* bh2 = UhS + (size_t)(nt * 128 + ar1 + 64) * 768 + afk;

  const int q = lane >> 4;
  const int l15 = lane & 15;
  int aoff[4], boff[4];
#pragma unroll
  for (int f = 0; f < 4; ++f) {
    {
      const int row = wm * 64 + f * 16 + l15;
      const int fr = (row ^ (row >> 2)) & 3;
      aoff[f] = row * 32 + ((q ^ fr) * 8);
    }
    {
      const int row = wn * 64 + f * 16 + l15;
      const int fr = (row ^ (row >> 2)) & 3;
      boff[f] = row * 32 + ((q ^ fr) * 8);
    }
  }

  f32x4 acc[4][4];
#pragma unroll
  for (int i = 0; i < 4; ++i)
#pragma unroll
    for (int j = 0; j < 4; ++j) acc[i][j] = (f32x4){0.f, 0.f, 0.f, 0.f};

  {
    const float4 a1a = *(const float4*)(asrc1);
    const float4 a1b = *(const float4*)(asrc1 + 4);
    const float4 a2a = *(const float4*)(asrc2);
    const float4 a2b = *(const float4*)(asrc2 + 4);
    const f16x8 vh1 = *(const f16x8*)(bh1);
    const f16x8 vh2 = *(const f16x8*)(bh2);
    f16x8 h1, h2;
    h1[0]=(_Float16)a1a.x; h1[1]=(_Float16)a1a.y; h1[2]=(_Float16)a1a.z; h1[3]=(_Float16)a1a.w;
    h1[4]=(_Float16)a1b.x; h1[5]=(_Float16)a1b.y; h1[6]=(_Float16)a1b.z; h1[7]=(_Float16)a1b.w;
    h2[0]=(_Float16)a2a.x; h2[1]=(_Float16)a2a.y; h2[2]=(_Float16)a2a.z; h2[3]=(_Float16)a2a.w;
    h2[4]=(_Float16)a2b.x; h2[5]=(_Float16)a2b.y; h2[6]=(_Float16)a2b.z; h2[7]=(_Float16)a2b.w;
    *(f16x8*)&Al[0][wA1] = h1;
    *(f16x8*)&Al[0][wA2] = h2;
    *(f16x8*)&Bh[0][wA1] = vh1;
    *(f16x8*)&Bh[0][wA2] = vh2;
  }
  __syncthreads();

  int cur = 0;
  for (int ks = 0; ks < 24; ++ks) {
    const int nxt = cur ^ 1;
    const bool more = (ks < 23);
    float4 a1a, a1b, a2a, a2b;
    f16x8 vh1, vh2;
    if (more) {
      const int ko = (ks + 1) * 32;
      a1a = *(const float4*)(asrc1 + ko);
      a1b = *(const float4*)(asrc1 + ko + 4);
      a2a = *(const float4*)(asrc2 + ko);
      a2b = *(const float4*)(asrc2 + ko + 4);
      vh1 = *(const f16x8*)(bh1 + ko);
      vh2 = *(const f16x8*)(bh2 + ko);
    }
    {
      const _Float16* Ab = &Al[cur][0];
      const _Float16* Bhb = &Bh[cur][0];
      f16x8 af[4], bhf[4];
#pragma unroll
      for (int fm = 0; fm < 4; ++fm) af[fm] = *(const f16x8*)&Ab[aoff[fm]];
#pragma unroll
      for (int fn = 0; fn < 4; ++fn) bhf[fn] = *(const f16x8*)&Bhb[boff[fn]];
#pragma unroll
      for (int fm = 0; fm < 4; ++fm)
#pragma unroll
        for (int fn = 0; fn < 4; ++fn)
          acc[fm][fn] = __builtin_amdgcn_mfma_f32_16x16x32_f16(af[fm], bhf[fn], acc[fm][fn], 0, 0, 0);
    }
    if (more) {
      f16x8 h1, h2;
      h1[0]=(_Float16)a1a.x; h1[1]=(_Float16)a1a.y; h1[2]=(_Float16)a1a.z; h1[3]=(_Float16)a1a.w;
      h1[4]=(_Float16)a1b.x; h1[5]=(_Float16)a1b.y; h1[6]=(_Float16)a1b.z; h1[7]=(_Float16)a1b.w;
      h2[0]=(_Float16)a2a.x; h2[1]=(_Float16)a2a.y; h2[2]=(_Float16)a2a.z; h2[3]=(_Float16)a2a.w;
      h2[4]=(_Float16)a2b.x; h2[5]=(_Float16)a2b.y; h2[6]=(_Float16)a2b.z; h2[7]=(_Float16)a2b.w;
      *(f16x8*)&Al[nxt][wA1] = h1;
      *(f16x8*)&Al[nxt][wA2] = h2;
      *(f16x8*)&Bh[nxt][wA1] = vh1;
      *(f16x8*)&Bh[nxt][wA2] = vh2;
    }
    barrier_lds_only();
    cur = nxt;
  }

  const int lq = lane >> 4;
  const int colbase = nt * 128 + wn * 64;
  const int ibase = mt * 128 + wm * 64;
  float* XUs = XU + (size_t)s * 4800 * 512;
  int rowm[4][4];
#pragma unroll
  for (int fm = 0; fm < 4; ++fm)
#pragma unroll
    for (int r = 0; r < 4; ++r) {
      const int i = ibase + fm * 16 + lq * 4 + r;
      rowm[fm][r] = (i < M) ? rms[i] : -1;
    }
#pragma unroll
  for (int fn = 0; fn < 4; ++fn) {
    const int col = colbase + fn * 16 + l15;
    const float bias = bU[s * 512 + col];
#pragma unroll
    for (int fm = 0; fm < 4; ++fm)
#pragma unroll
      for (int r = 0; r < 4; ++r) {
        const int row = rowm[fm][r];
        if (row >= 0) XUs[(size_t)row * 512 + col] = acc[fm][fn][r] + bias;
      }
  }
}

// ---------------------------------------------------------------------------
// K2 v9 (REVERT to round-14 state): single 16-seq group per block, 80 blocks,
//   LDS-only per-step barrier, XU tile double-buffered in LDS, single-product
//   MFMA with 2-deep split chains, deferred global stores.
// ---------------------------------------------------------------------------
__global__ __launch_bounds__(512, 2) void k2_tlstm(const _Float16* __restrict__ Wfh,
                                                   const _Float16* __restrict__ Dfh,
                                                   const float* __restrict__ ball,
                                                   const float* __restrict__ bd,
                                                   const float* __restrict__ XU,
                                                   const float* __restrict__ times,
                                                   const int* __restrict__ lens,
                                                   float* __restrict__ outs,
                                                   float* __restrict__ hn) {
  const int s = blockIdx.x;
  const int mg = blockIdx.y;
  const int tid = threadIdx.x;
  const int w = tid >> 6, l = tid & 63;

  __shared__ _Float16 hhb[2][2048];
  __shared__ _Float16 chb[2][2048];
  __shared__ float xut[2][16 * 516];
  __shared__ float tsh[16 * 32];
  __shared__ int lensh[16];

  if (tid < 16) {
    const int n = mg * 16 + tid;
    lensh[tid] = lens[((n / 5) * 8 + s) * 5 + (n % 5)];
  }
  if (tid < 480) {
    const int r = tid / 30, c = tid % 30;
    const int n = mg * 16 + r;
    tsh[r * 32 + c] = times[(((n / 5) * 8 + s) * 5 + (n % 5)) * 30 + c];
  }

  f16x8 Bh[16], Dh[4];
  {
    const _Float16* wb = Wfh + (size_t)(s * 8 + w) * 8192 + l * 8;
    const _Float16* db = Dfh + (size_t)(s * 8 + w) * 2048 + l * 8;
#pragma unroll
    for (int c = 0; c < 16; ++c) Bh[c] = *(const f16x8*)&wb[c * 512];
#pragma unroll
    for (int c = 0; c < 4; ++c) Dh[c] = *(const f16x8*)&db[c * 512];
  }

  const int hd = w * 16 + (l & 15);
  const int rq0 = (l >> 4) * 4;
  const int lp0 = rq0 | (((hd >> 3) & 3) << 4);
  const int eoff0 = ((hd >> 5) * 64 + lp0) * 8 + (hd & 7);

#pragma unroll
  for (int q = 0; q < 4; ++q) {
    hhb[0][eoff0 + q * 8] = (_Float16)0.f;
    chb[0][eoff0 + q * 8] = (_Float16)0.f;
  }

  int n_q[4];
#pragma unroll
  for (int q = 0; q < 4; ++q) n_q[q] = mg * 16 + rq0 + q;
  float blr[4];
#pragma unroll
  for (int g = 0; g < 4; ++g) blr[g] = ball[s * 512 + g * 128 + hd];
  const float bdj = bd[s * 128 + hd];

  const int sr = tid >> 5;
  const int sc = tid & 31;
  const float* xsrc = XU + (size_t)(s * 160 + mg * 16 + sr) * 30 * 512 + sc * 4;
  const int xdst = sr * 516 + sc * 4;

  __syncthreads();

  int len_q[4];
  int maxlen = 0;
#pragma unroll
  for (int i = 0; i < 16; ++i) maxlen = max(maxlen, lensh[i]);
#pragma unroll
  for (int q = 0; q < 4; ++q) len_q[q] = lensh[rq0 + q];

  float creg[4] = {0.f, 0.f, 0.f, 0.f};
  float hreg[4] = {0.f, 0.f, 0.f, 0.f};
  float oprev[4] = {0.f, 0.f, 0.f, 0.f};

  {
    float4 v0 = *(const float4*)(xsrc);
    float4 v1 = *(const float4*)(xsrc + 128);
    float4 v2 = *(const float4*)(xsrc + 256);
    float4 v3 = *(const float4*)(xsrc + 384);
    *(float4*)&xut[0][xdst]       = v0;
    *(float4*)&xut[0][xdst + 128] = v1;
    *(float4*)&xut[0][xdst + 256] = v2;
    *(float4*)&xut[0][xdst + 384] = v3;
  }
  __syncthreads();

  for (int t = 0; t < maxlen; ++t) {
    const int p = t & 1;

    // deferred global stores for step t-1 (fly across the LDS-only barrier)
    if (t > 0) {
      const int tp = t - 1;
#pragma unroll
      for (int q = 0; q < 4; ++q) {
        if (tp < len_q[q]) {
          outs[((size_t)(s * 160 + n_q[q]) * 30 + tp) * 128 + hd] = oprev[q];
          if (tp == len_q[q] - 1) hn[(size_t)(s * 160 + n_q[q]) * 128 + hd] = oprev[q];
        }
      }
    }

    // prefetch XU tile for t+1
    float4 pv0, pv1, pv2, pv3;
    const bool more = (t + 1 < maxlen);
    if (more) {
      const float* xp = xsrc + (size_t)(t + 1) * 512;
      pv0 = *(const float4*)(xp);
      pv1 = *(const float4*)(xp + 128);
      pv2 = *(const float4*)(xp + 256);
      pv3 = *(const float4*)(xp + 384);
    }

    // ---- M phase: single product per gate, 2-deep split chains ----
    f32x4 amA[4], amB[4], dm;
#pragma unroll
    for (int g = 0; g < 4; ++g) {
      amA[g] = (f32x4){0.f, 0.f, 0.f, 0.f};
      amB[g] = (f32x4){0.f, 0.f, 0.f, 0.f};
    }
    dm = (f32x4){0.f, 0.f, 0.f, 0.f};
#pragma unroll
    for (int kt = 0; kt < 2; ++kt) {
      const f16x8 ah0 = *(const f16x8*)&hhb[p][(kt * 64 + l) * 8];
      const f16x8 ah1 = *(const f16x8*)&hhb[p][((kt + 2) * 64 + l) * 8];
      const f16x8 cf0 = *(const f16x8*)&chb[p][(kt * 64 + l) * 8];
      const f16x8 cf1 = *(const f16x8*)&chb[p][((kt + 2) * 64 + l) * 8];
#pragma unroll
      for (int g = 0; g < 4; ++g) {
        amA[g] = __builtin_amdgcn_mfma_f32_16x16x32_f16(ah0, Bh[kt * 4 + g], amA[g], 0, 0, 0);
        amB[g] = __builtin_amdgcn_mfma_f32_16x16x32_f16(ah1, Bh[(kt + 2) * 4 + g], amB[g], 0, 0, 0);
      }
      dm = __builtin_amdgcn_mfma_f32_16x16x32_f16(cf0, Dh[kt], dm, 0, 0, 0);
      dm = __builtin_amdgcn_mfma_f32_16x16x32_f16(cf1, Dh[kt + 2], dm, 0, 0, 0);
    }

    // ---- E phase ----
#pragma unroll
    for (int q = 0; q < 4; ++q) {
      if (t < len_q[q]) {
        const float* xr = &xut[p][(rq0 + q) * 516 + hd];
        const float tt = tsh[(rq0 + q) * 32 + t];
        const float cs1 = tanhf_(dm[q] + bdj);
        const float f  = sigf(amA[0][q] + amB[0][q] + xr[0]   + blr[0]);
        const float ii = sigf(amA[1][q] + amB[1][q] + xr[128] + blr[1]);
        const float o  = sigf(amA[2][q] + amB[2][q] + xr[256] + blr[2]);
        const float ct = sigf(amA[3][q] + amB[3][q] + xr[384] + blr[3]);
        const float c2 = f * (creg[q] + cs1 * (tt - 1.f)) + ii * ct;
        creg[q] = c2;
        hreg[q] = o * tanhf_(c2);
        oprev[q] = o;
      }
      hhb[p ^ 1][eoff0 + q * 8] = (_Float16)hreg[q];
      chb[p ^ 1][eoff0 + q * 8] = (_Float16)creg[q];
    }

    if (more) {
      *(float4*)&xut[p ^ 1][xdst]       = pv0;
      *(float4*)&xut[p ^ 1][xdst + 128] = pv1;
      *(float4*)&xut[p ^ 1][xdst + 256] = pv2;
      *(float4*)&xut[p ^ 1][xdst + 384] = pv3;
    }
    barrier_lds_only();
  }

  {
    const int tp = maxlen - 1;
#pragma unroll
    for (int q = 0; q < 4; ++q) {
      if (tp >= 0 && tp < len_q[q]) {
        outs[((size_t)(s * 160 + n_q[q]) * 30 + tp) * 128 + hd] = oprev[q];
        if (tp == len_q[q] - 1) hn[(size_t)(s * 160 + n_q[q]) * 128 + hd] = oprev[q];
      }
    }
  }
}

// ---------------------------------------------------------------------------
// K3 v7: MFMA attention-1 with LDS-staged o-tile (unchanged).
// ---------------------------------------------------------------------------
__global__ __launch_bounds__(512, 2) void k3_attn1(const _Float16* __restrict__ W1f,
                                                   const _Float16* __restrict__ W2f,
                                                   const float* __restrict__ b1,
                                                   const float* __restrict__ b2,
                                                   const float* __restrict__ V,
                                                   const float* __restrict__ outs,
                                                   const float* __restrict__ hn,
                                                   const int* __restrict__ lens,
                                                   float* __restrict__ ctx) {
  const int s = blockIdx.x;
  const int sg = blockIdx.y;
  const int tid = threadIdx.x;
  const int w = tid >> 6, l = tid & 63;
  const int nbase = s * 160 + sg * 8;

  __shared__ _Float16 osh[32768];
  __shared__ float u[16][132];
  __shared__ float red[8][8][32];
  __shared__ float score[8][32];
  __shared__ int lensh[8];

  if (tid < 8) {
    const int n = sg * 8 + tid;
    lensh[tid] = lens[((n / 5) * 8 + s) * 5 + (n % 5)];
  }

#pragma unroll
  for (int i = 0; i < 8; ++i) {
    const int c = tid + i * 512;
    const int nl = c >> 9;
    const int th = (c >> 8) & 1;
    const int kt = (c >> 6) & 3;
    const int lp = c & 63;
    const int t15 = lp & 15;
    const int kb = kt * 32 + (lp >> 4) * 8;
    const int t = th * 16 + t15;
    f16x8 v;
    if (t < 30) {
      const float* src = outs + ((size_t)(nbase + nl) * 30 + t) * 128 + kb;
      const float4 a = *(const float4*)(src);
      const float4 b = *(const float4*)(src + 4);
      v[0]=(_Float16)a.x; v[1]=(_Float16)a.y; v[2]=(_Float16)a.z; v[3]=(_Float16)a.w;
      v[4]=(_Float16)b.x; v[5]=(_Float16)b.y; v[6]=(_Float16)b.z; v[7]=(_Float16)b.w;
    } else {
      v = (f16x8){(_Float16)0.f,(_Float16)0.f,(_Float16)0.f,(_Float16)0.f,
                  (_Float16)0.f,(_Float16)0.f,(_Float16)0.f,(_Float16)0.f};
    }
    *(f16x8*)&osh[c * 8] = v;
  }

  f16x8 W1r[4], W2r[4];
  {
    const _Float16* w1b = W1f + (size_t)(s * 8 + w) * 2048 + l * 8;
    const _Float16* w2b = W2f + (size_t)(s * 8 + w) * 2048 + l * 8;
#pragma unroll
    for (int kt = 0; kt < 4; ++kt) {
      W1r[kt] = *(const f16x8*)&w1b[kt * 512];
      W2r[kt] = *(const f16x8*)&w2b[kt * 512];
    }
  }

  const int hd = w * 16 + (l & 15);
  const float Vhd = V[s * 128 + hd];
  const float b12 = b1[s * 128 + hd] + b2[s * 128 + hd];
  const int kc = (l >> 4) << 3;

  {
    const int rsrc = min(l & 15, 7);
    f32x4 dm = (f32x4){0.f, 0.f, 0.f, 0.f};
#pragma unroll
    for (int kt = 0; kt < 4; ++kt) {
      const float* hp = hn + (size_t)(nbase + rsrc) * 128 + kt * 32 + kc;
      const float4 a = *(const float4*)(hp);
      const float4 b = *(const float4*)(hp + 4);
      f16x8 ah;
      ah[0]=(_Float16)a.x; ah[1]=(_Float16)a.y; ah[2]=(_Float16)a.z; ah[3]=(_Float16)a.w;
      ah[4]=(_Float16)b.x; ah[5]=(_Float16)b.y; ah[6]=(_Float16)b.z; ah[7]=(_Float16)b.w;
      dm = __builtin_amdgcn_mfma_f32_16x16x32_f16(ah, W1r[kt], dm, 0, 0, 0);
    }
#pragma unroll
    for (int q = 0; q < 4; ++q) u[(l >> 4) * 4 + q][hd] = dm[q] + b12;
  }
  __syncthreads();

#pragma unroll
  for (int m = 0; m < 16; ++m) {
    const int nl = m >> 1, th = m & 1;
    const int cbase = ((nl * 2 + th) * 4) * 64;
    f32x4 acc = (f32x4){0.f, 0.f, 0.f, 0.f};
#pragma unroll
    for (int kt = 0; kt < 4; ++kt) {
      const f16x8 ah = *(const f16x8*)&osh[(cbase + kt * 64 + l) * 8];
      acc = __builtin_amdgcn_mfma_f32_16x16x32_f16(ah, W2r[kt], acc, 0, 0, 0);
    }
    const float uv = u[nl][hd];
#pragma unroll
    for (int q = 0; q < 4; ++q) {
      float p = tanhf_(acc[q] + uv) * Vhd;
      p += __shfl_xor(p, 1);
      p += __shfl_xor(p, 2);
      p += __shfl_xor(p, 4);
      p += __shfl_xor(p, 8);
      const int t = th * 16 + (l >> 4) * 4 + q;
      if ((l & 15) == 0 && t < 30) red[w][nl][t] = p;
    }
  }
  __syncthreads();

  if (tid < 256) {
    const int nl = tid >> 5, t = tid & 31;
    if (t < 30) {
      float sc = 0.f;
#pragma unroll
      for (int ww = 0; ww < 8; ++ww) sc += red[ww][nl][t];
      score[nl][t] = sc;
    }
  }
  __syncthreads();

  {
    const int nl = tid >> 6, jg = tid & 63;
    const int len = lensh[nl];
    float mx = -1e30f;
    for (int t = 0; t < len; ++t) mx = fmaxf(mx, score[nl][t]);
    const float* ob = outs + (size_t)(nbase + nl) * 30 * 128 + jg * 2;
    float sum = 0.f;
    float cx0 = 0.f, cx1 = 0.f;
    for (int t = 0; t < len; ++t) {
      const float e = __expf(score[nl][t] - mx);
      sum += e;
      const float2 o2 = *(const float2*)(ob + (size_t)t * 128);
      cx0 += e * o2.x; cx1 += e * o2.y;
    }
    const float r = rcp_(sum);
    float2 res = {cx0 * r, cx1 * r};
    *(float2*)&ctx[(size_t)(nbase + nl) * 128 + jg * 2] = res;
  }
}

// ---------------------------------------------------------------------------
// K4: LSTM over D=5 (unchanged).
// ---------------------------------------------------------------------------
__global__ __launch_bounds__(512, 2) void k4_lstm2(const float* __restrict__ Wih,
                                                   const float* __restrict__ bih,
                                                   const float* __restrict__ Whh,
                                                   const float* __restrict__ bhh,
                                                   const float* __restrict__ ctx,
                                                   float* __restrict__ hsout,
                                                   float* __restrict__ hlast) {
  const int s = blockIdx.y, b = blockIdx.x;
  const int gj = threadIdx.x;
  __shared__ float xs[5][128];
  __shared__ float hsm[128];
  __shared__ float gsh[512];

  for (int idx = gj; idx < 640; idx += 512)
    (&xs[0][0])[idx] = ctx[(size_t)(s * 160 + b * 5) * 128 + idx];
  if (gj < 128) hsm[gj] = 0.f;
  __syncthreads();

  const float* Wis = Wih + (size_t)s * 65536;
  const float* Whs = Whh + (size_t)s * 65536;
  const float bias = bih[s * 512 + gj] + bhh[s * 512 + gj];
  float xw[5] = {bias, bias, bias, bias, bias};
  float whh[128];
#pragma unroll
  for (int k = 0; k < 128; ++k) {
    const float wi = Wis[k * 512 + gj];
    whh[k] = Whs[k * 512 + gj];
#pragma unroll
    for (int dd = 0; dd < 5; ++dd) xw[dd] += xs[dd][k] * wi;
  }

  float c = 0.f;
  for (int dd = 0; dd < 5; ++dd) {
    float g = xw[dd];
#pragma unroll
    for (int k = 0; k < 128; ++k) g += hsm[k] * whh[k];
    gsh[gj] = g;
    __syncthreads();
    if (gj < 128) {
      const int j = gj;
      const float c2 = sigf(gsh[128 + j]) * c + sigf(gsh[j]) * tanhf_(gsh[256 + j]);
      const float h2 = sigf(gsh[384 + j]) * tanhf_(c2);
      c = c2;
      hsm[j] = h2;
      hsout[((size_t)(s * 32 + b) * 5 + dd) * 128 + j] = h2;
      if (dd == 4) hlast[(size_t)(s * 32 + b) * 128 + j] = h2;
    }
    __syncthreads();
  }
}

// ---------------------------------------------------------------------------
// K5: attention 2 + output MLP (unchanged).
// ---------------------------------------------------------------------------
__global__ __launch_bounds__(128) void k5_attn2(const float* __restrict__ W1,
                                                const float* __restrict__ b1,
                                                const float* __restrict__ W2,
                                                const float* __restrict__ b2,
                                                const float* __restrict__ V,
                                                const float* __restrict__ bV,
                                                const float* __restrict__ x1W,
                                                const float* __restrict__ x1b,
                                                const float* __restrict__ x2W,
                                                const float* __restrict__ x2b,
                                                const float* __restrict__ hs,
                                                const float* __restrict__ hlast,
                                                float* __restrict__ y) {
  const int s = blockIdx.y, b = blockIdx.x, j = threadIdx.x;
  __shared__ float hl[128], hsm[5][128], t1[128], cs2[128], sc[5], red[2];
  hl[j] = hlast[(size_t)(s * 32 + b) * 128 + j];
  const float* hsrc = hs + (size_t)(s * 32 + b) * 640;
  for (int idx = j; idx < 640; idx += 128) (&hsm[0][0])[idx] = hsrc[idx];
  __syncthreads();

  const float* W1s = W1 + (size_t)s * 16384;
  const float* W2s = W2 + (size_t)s * 16384;
  float u = b1[s * 128 + j] + b2[s * 128 + j];
  for (int k = 0; k < 128; ++k) u += hl[k] * W1s[k * 128 + j];
  const float Vj = V[s * 128 + j];
  const int lane = j & 63, wid = j >> 6;

  for (int d = 0; d < 5; ++d) {
    float a = u;
    for (int k = 0; k < 128; ++k) a += hsm[d][k] * W2s[k * 128 + j];
    float p = tanhf_(a) * Vj;
#pragma unroll
    for (int off = 32; off; off >>= 1) p += __shfl_down(p, off);
    if (lane == 0) red[wid] = p;
    __syncthreads();
    if (j == 0) sc[d] = red[0] + red[1] + bV[s];
    __syncthreads();
  }

  float m = -1e30f;
  for (int d = 0; d < 5; ++d) m = fmaxf(m, sc[d]);
  float sum = 0.f;
  for (int d = 0; d < 5; ++d) sum += __expf(sc[d] - m);
  float cx = 0.f;
  for (int d = 0; d < 5; ++d) cx += __expf(sc[d] - m) * hsm[d][j];
  cs2[j] = cx / sum;
  __syncthreads();

  float a = x1b[s * 128 + j];
  for (int k = 0; k < 128; ++k) a += cs2[k] * x1W[(size_t)s * 16384 + k * 128 + j];
  t1[j] = fmaxf(a, 0.f);
  __syncthreads();

  if (j < 64) {
    float yy = x2b[s * 64 + j];
    for (int k = 0; k < 128; ++k) yy += t1[k] * x2W[(size_t)(s * 128 + k) * 64 + j];
    y[(size_t)(s * 32 + b) * 64 + j] = yy;
  }
}

// ---------------------------------------------------------------------------
// K6: final combine (unchanged).
// ---------------------------------------------------------------------------
__global__ __launch_bounds__(256) void k6_final(const float* __restrict__ stock,
                                                const float* __restrict__ h1W,
                                                const float* __restrict__ h1b,
                                                const float* __restrict__ h2W,
                                                const float* __restrict__ h2b,
                                                const float* __restrict__ hcW,
                                                const float* __restrict__ hcb,
                                                const float* __restrict__ yws,
                                                float* __restrict__ out) {
  const int tid = threadIdx.x;
  __shared__ float sf[32 * 17];
  __shared__ float hid[32 * 64];
  __shared__ float xs[32 * 32];
  for (int idx = tid; idx < 544; idx += 256) sf[idx] = stock[idx];
  __syncthreads();
  for (int idx = tid; idx < 2048; idx += 256) {
    const int b = idx >> 6, k = idx & 63;
    float a = h1b[k];
    for (int q = 0; q < 17; ++q) a += sf[b * 17 + q] * h1W[q * 64 + k];
    hid[idx] = fmaxf(a, 0.f);
  }
  __syncthreads();
  for (int idx = tid; idx < 1024; idx += 256) {
    const int b = idx >> 5, mm = idx & 31;
    float a = h2b[mm];
    for (int k = 0; k < 64; ++k) a += hid[b * 64 + k] * h2W[k * 32 + mm];
    xs[idx] = a;
  }
  __syncthreads();
  {
    const int b = tid >> 3, o = tid & 7;
    float a = hcb[o];
    for (int c = 0; c < 32; ++c) a += xs[b * 32 + c] * hcW[c * 8 + o];
    for (int c = 32; c < 544; ++c) {
      const int ss = (c - 32) >> 6, k = (c - 32) & 63;
      a += yws[((size_t)ss * 32 + b) * 64 + k] * hcW[c * 8 + o];
    }
    out[tid] = tanhf_(a);
  }
}

// ---------------------------------------------------------------------------
extern "C" void kernel_launch(void* const* d_in, const int* in_sizes, int n_in,
                              void* d_out, int out_size, void* d_ws, size_t ws_size,
                              hipStream_t stream) {
  (void)in_sizes; (void)n_in; (void)out_size; (void)ws_size;
  const float* stock = (const float*)d_in[0];
  const float* sent  = (const float*)d_in[1];
  const float* times = (const float*)d_in[2];
  const int*   lens  = (const int*)d_in[3];
  const float* tlWall = (const float*)d_in[4];
  const float* tlball = (const float*)d_in[5];
  const float* tlUall = (const float*)d_in[6];
  const float* tlbU   = (const float*)d_in[7];
  const float* tlWd   = (const float*)d_in[8];
  const float* tlbd   = (const float*)d_in[9];
  const float* a1W1 = (const float*)d_in[10];
  const float* a1b1 = (const float*)d_in[11];
  const float* a1W2 = (const float*)d_in[12];
  const float* a1b2 = (const float*)d_in[13];
  const float* a1V  = (const float*)d_in[14];
  const float* a1bV = (const float*)d_in[15];
  const float* l2Wih = (const float*)d_in[16];
  const float* l2bih = (const float*)d_in[17];
  const float* l2Whh = (const float*)d_in[18];
  const float* l2bhh = (const float*)d_in[19];
  const float* a2W1 = (const float*)d_in[20];
  const float* a2b1 = (const float*)d_in[21];
  const float* a2W2 = (const float*)d_in[22];
  const float* a2b2 = (const float*)d_in[23];
  const float* a2V  = (const float*)d_in[24];
  const float* a2bV = (const float*)d_in[25];
  const float* x1W  = (const float*)d_in[26];
  const float* x1b  = (const float*)d_in[27];
  const float* x2W  = (const float*)d_in[28];
  const float* x2b  = (const float*)d_in[29];
  const float* h1W  = (const float*)d_in[30];
  const float* h1b  = (const float*)d_in[31];
  const float* h2W  = (const float*)d_in[32];
  const float* h2b  = (const float*)d_in[33];
  const float* hcW  = (const float*)d_in[34];
  const float* hcb  = (const float*)d_in[35];

  float* ws = (float*)d_ws;
  float* XU    = ws;               // 8*160*30*512   = 19,660,800
  float* outs  = XU + 19660800;    // 8*160*30*128   =  4,915,200
  float* hnb   = outs + 4915200;   // 8*160*128      =    163,840
  float* ctx   = hnb + 163840;     // 8*160*128      =    163,840
  float* hsb   = ctx + 163840;     // 8*32*5*128     =    163,840
  float* hlast = hsb + 163840;     // 8*32*128       =     32,768
  float* yb    = hlast + 32768;    // 8*32*64        =     16,384
  _Float16* Uhw = (_Float16*)(yb + 16384);    // 8*512*768 halfs
  _Float16* Wfh = Uhw + 8 * 512 * 768;        // 8*8*8192 halfs
  _Float16* Dfh = Wfh + 8 * 8 * 8192;         // 8*8*2048 halfs
  _Float16* W1f = Dfh + 8 * 8 * 2048;         // 8*8*2048 halfs
  _Float16* W2f = W1f + 8 * 8 * 2048;         // 8*8*2048 halfs
  int* rowmap = (int*)(W2f + 8 * 8 * 2048);   // 8*4800 ints
  int* Msd    = rowmap + 8 * 4800;            // 8 ints

  k0_rowmap<<<8, 256, 0, stream>>>(lens, rowmap, Msd);
  k0_usplit<<<dim3(12, 8, 8), 256, 0, stream>>>(tlUall, Uhw);
  k0_wprep<<<dim3(8, 8), 256, 0, stream>>>(tlWall, tlWd, Wfh, Dfh);
  k0_aprep<<<dim3(8, 8), 256, 0, stream>>>(a1W1, a1W2, W1f, W2f);
  k1_xu<<<dim3(8, 152), 256, 0, stream>>>(sent, Uhw, tlbU, rowmap, Msd, XU);
  k2_tlstm<<<dim3(8, 10), 512, 0, stream>>>(Wfh, Dfh, tlball, tlbd, XU, times, lens, outs, hnb);
  k3_attn1<<<dim3(8, 20), 512, 0, stream>>>(W1f, W2f, a1b1, a1b2, a1V, outs, hnb, lens, ctx);
  k4_lstm2<<<dim3(32, 8), 512, 0, stream>>>(l2Wih, l2bih, l2Whh, l2bhh, ctx, hsb, hlast);
  k5_attn2<<<dim3(32, 8), 128, 0, stream>>>(a2W1, a2b1, a2W2, a2b2, a2V, a2bV, x1W, x1b, x2W, x2b, hsb, hlast, yb);
  k6_final<<<1, 256, 0, stream>>>(stock, h1W, h1b, h2W, h2b, hcW, hcb, yb, (float*)d_out);
}

// Round 17
// 198.214 us; speedup vs baseline: 1.3406x; 1.0893x over previous
//
#include <hip/hip_runtime.h>
#include <cstddef>

// Problem constants: S=8, B=32, D=5, T=30, E=768, H=128, 4H=512.

typedef __attribute__((ext_vector_type(8))) _Float16 f16x8;
typedef __attribute__((ext_vector_type(4))) _Float16 f16x4;
typedef __attribute__((ext_vector_type(2))) _Float16 f16x2;
typedef __attribute__((ext_vector_type(4))) float f32x4;

__device__ __forceinline__ float rcp_(float x) { return __builtin_amdgcn_rcpf(x); }
__device__ __forceinline__ float sigf(float x) { return rcp_(1.0f + __expf(-x)); }
__device__ __forceinline__ float tanhf_(float x) { return 1.0f - 2.0f * rcp_(__expf(2.0f * x) + 1.0f); }

// LDS-only barrier: drains lgkmcnt but NOT vmcnt (global ops stay in flight).
__device__ __forceinline__ void barrier_lds_only() {
  asm volatile("s_waitcnt lgkmcnt(0)" ::: "memory");
  __builtin_amdgcn_s_barrier();
  __builtin_amdgcn_sched_barrier(0);
}

// ---------------------------------------------------------------------------
// K0r: per-stock compacted row map: rows (n,t) with t < len[s,n].
// ---------------------------------------------------------------------------
__global__ __launch_bounds__(256) void k0_rowmap(const int* __restrict__ lens,
                                                 int* __restrict__ rowmap,
                                                 int* __restrict__ Ms) {
  const int s = blockIdx.x;
  const int tid = threadIdx.x;
  __shared__ int st[160];
  __shared__ int ln[160];
  if (tid < 160) {
    const int b = tid / 5, d = tid % 5;
    ln[tid] = lens[(b * 8 + s) * 5 + d];
  }
  __syncthreads();
  if (tid == 0) {
    int run = 0;
    for (int n = 0; n < 160; ++n) { st[n] = run; run += ln[n]; }
    Ms[s] = run;
  }
  __syncthreads();
  if (tid < 160) {
    const int base = st[tid], l = ln[tid];
    for (int t = 0; t < l; ++t) rowmap[s * 4800 + base + t] = tid * 30 + t;
  }
}

// ---------------------------------------------------------------------------
// K0: transpose U to fp16 (hi only) via LDS tiles (for k1).
// ---------------------------------------------------------------------------
__global__ __launch_bounds__(256) void k0_usplit(const float* __restrict__ U,
                                                 _Float16* __restrict__ Uh) {
  const int s = blockIdx.z;
  const int k0 = blockIdx.x * 64;
  const int n0 = blockIdx.y * 64;
  const int tid = threadIdx.x;
  __shared__ _Float16 Th[64 * 66];
  const float* Us = U + (size_t)s * 768 * 512;
#pragma unroll
  for (int rep = 0; rep < 16; ++rep) {
    const int idx = rep * 256 + tid;
    const int r = idx >> 6, c = idx & 63;
    Th[r * 66 + c] = (_Float16)Us[(size_t)(k0 + r) * 512 + n0 + c];
  }
  __syncthreads();
  _Float16* uhs = Uh + (size_t)s * 512 * 768;
#pragma unroll
  for (int rep = 0; rep < 8; ++rep) {
    const int idx = rep * 256 + tid;
    const int nn = idx >> 5;
    const int kp = (idx & 31) * 2;
    const f16x2 h2 = {Th[kp * 66 + nn], Th[(kp + 1) * 66 + nn]};
    *(f16x2*)&uhs[(size_t)(n0 + nn) * 768 + k0 + kp] = h2;
  }
}

// ---------------------------------------------------------------------------
// K0w: pack Wall (hi only) and Wd (hi) into MFMA B-fragment-linear layout.
// ---------------------------------------------------------------------------
__global__ __launch_bounds__(256) void k0_wprep(const float* __restrict__ Wall,
                                                const float* __restrict__ Wd,
                                                _Float16* __restrict__ Wfh,
                                                _Float16* __restrict__ Dfh) {
  const int w = blockIdx.x, s = blockIdx.y;
  const int tid = threadIdx.x;
  const float* Ws = Wall + (size_t)s * 65536;
  _Float16* oh = Wfh + (size_t)(s * 8 + w) * 8192;
  for (int c = tid; c < 1024; c += 256) {
    const int kt = c >> 8, nt = (c >> 6) & 3, l = c & 63;
    const int n = nt * 128 + w * 16 + (l & 15);   // gate-major per wave
    const int kb = kt * 32 + ((l >> 4) << 3);
    f16x8 hv;
#pragma unroll
    for (int e = 0; e < 8; ++e) hv[e] = (_Float16)Ws[(size_t)(kb + e) * 512 + n];
    *(f16x8*)&oh[c * 8] = hv;
  }
  {
    const float* Ds = Wd + (size_t)s * 16384;
    _Float16* od = Dfh + (size_t)(s * 8 + w) * 2048;
    const int c = tid;
    const int kt = c >> 6, l = c & 63;
    const int n = w * 16 + (l & 15);
    const int kb = kt * 32 + ((l >> 4) << 3);
    f16x8 hv;
#pragma unroll
    for (int e = 0; e < 8; ++e) hv[e] = (_Float16)Ds[(size_t)(kb + e) * 128 + n];
    *(f16x8*)&od[c * 8] = hv;
  }
}

// ---------------------------------------------------------------------------
// K0a: pack a1_W1 and a1_W2 into per-wave 16-col B-frag layout.
// ---------------------------------------------------------------------------
__global__ __launch_bounds__(256) void k0_aprep(const float* __restrict__ W1,
                                                const float* __restrict__ W2,
                                                _Float16* __restrict__ W1f,
                                                _Float16* __restrict__ W2f) {
  const int w = blockIdx.x, s = blockIdx.y;
  const int c = threadIdx.x;          // 0..255 = kt*64 + l
  const int kt = c >> 6, l = c & 63;
  const int n = w * 16 + (l & 15);
  const int kb = kt * 32 + ((l >> 4) << 3);
  const float* W1s = W1 + (size_t)s * 16384;
  const float* W2s = W2 + (size_t)s * 16384;
  f16x8 v1, v2;
#pragma unroll
  for (int e = 0; e < 8; ++e) {
    v1[e] = (_Float16)W1s[(size_t)(kb + e) * 128 + n];
    v2[e] = (_Float16)W2s[(size_t)(kb + e) * 128 + n];
  }
  *(f16x8*)&W1f[(size_t)(s * 8 + w) * 2048 + c * 8] = v1;
  *(f16x8*)&W2f[(size_t)(s * 8 + w) * 2048 + c * 8] = v2;
}

// ---------------------------------------------------------------------------
// K1 v5: XU = x @ U + bU via MFMA (unchanged).
// ---------------------------------------------------------------------------
__global__ __launch_bounds__(256, 4) void k1_xu(const float* __restrict__ sent,
                                                const _Float16* __restrict__ Uh,
                                                const float* __restrict__ bU,
                                                const int* __restrict__ rowmap,
                                                const int* __restrict__ Ms,
                                                float* __restrict__ XU) {
  const int s = blockIdx.x;
  const int M = Ms[s];
  const int nt = blockIdx.y & 3;
  const int mt = blockIdx.y >> 2;
  if (mt * 128 >= M) return;
  const int tid = threadIdx.x;
  const int lane = tid & 63, wid = tid >> 6;
  const int wm = wid >> 1, wn = wid & 1;

  __shared__ _Float16 Al[2][128 * 32];
  __shared__ _Float16 Bh[2][128 * 32];

  const int ar1 = tid >> 2;
  const int chk = tid & 3;
  const int afk = chk * 8;
  const int fw = (ar1 ^ (ar1 >> 2)) & 3;
  const int wA1 = ar1 * 32 + ((chk ^ fw) * 8);
  const int wA2 = wA1 + 64 * 32;

  const int* rms = rowmap + s * 4800;
  const float* asrc1;
  const float* asrc2;
  {
    int i1 = mt * 128 + ar1; if (i1 > M - 1) i1 = M - 1;
    const int grow = rms[i1];
    const int nn = grow / 30, tt = grow % 30, ab = nn / 5, ad = nn % 5;
    asrc1 = sent + (size_t)((((ab * 8 + s) * 5 + ad) * 30) + tt) * 768 + afk;
  }
  {
    int i2 = mt * 128 + ar1 + 64; if (i2 > M - 1) i2 = M - 1;
    const int grow = rms[i2];
    const int nn = grow / 30, tt = grow % 30, ab = nn / 5, ad = nn % 5;
    asrc2 = sent + (size_t)((((ab * 8 + s) * 5 + ad) * 30) + tt) * 768 + afk;
  }
  const _Float16* UhS = Uh + (size_t)s * 512 * 768;
  const _Float16* bh1 = UhS + (size_t)(nt * 128 + ar1) * 768 + afk;
  const _Float16* bh2 = UhS + (size_t)(nt * 128 + ar1 + 64) * 768 + afk;

  const int q = lane >> 4;
  const int l15 = lane & 15;
  int aoff[4], boff[4];
#pragma unroll
  for (int f = 0; f < 4; ++f) {
    {
      const int row = wm * 64 + f * 16 + l15;
      const int fr = (row ^ (row >> 2)) & 3;
      aoff[f] = row * 32 + ((q ^ fr) * 8);
    }
    {
      const int row = wn * 64 + f * 16 + l15;
      const int fr = (row ^ (row >> 2)) & 3;
      boff[f] = row * 32 + ((q ^ fr) * 8);
    }
  }

  f32x4 acc[4][4];
#pragma unroll
  for (int i = 0; i < 4; ++i)
#pragma unroll
    for (int j = 0; j < 4; ++j) acc[i][j] = (f32x4){0.f, 0.f, 0.f, 0.f};

  {
    const float4 a1a = *(const float4*)(asrc1);
    const float4 a1b = *(const float4*)(asrc1 + 4);
    const float4 a2a = *(const float4*)(asrc2);
    const float4 a2b = *(const float4*)(asrc2 + 4);
    const f16x8 vh1 = *(const f16x8*)(bh1);
    const f16x8 vh2 = *(const f16x8*)(bh2);
    f16x8 h1, h2;
    h1[0]=(_Float16)a1a.x; h1[1]=(_Float16)a1a.y; h1[2]=(_Float16)a1a.z; h1[3]=(_Float16)a1a.w;
    h1[4]=(_Float16)a1b.x; h1[5]=(_Float16)a1b.y; h1[6]=(_Float16)a1b.z; h1[7]=(_Float16)a1b.w;
    h2[0]=(_Float16)a2a.x; h2[1]=(_Float16)a2a.y; h2[2]=(_Float16)a2a.z; h2[3]=(_Float16)a2a.w;
    h2[4]=(_Float16)a2b.x; h2[5]=(_Float16)a2b.y; h2[6]=(_Float16)a2b.z; h2[7]=(_Float16)a2b.w;
    *(f16x8*)&Al[0][wA1] = h1;
    *(f16x8*)&Al[0][wA2] = h2;
    *(f16x8*)&Bh[0][wA1] = vh1;
    *(f16x8*)&Bh[0][wA2] = vh2;
  }
  __syncthreads();

  int cur = 0;
  for (int ks = 0; ks < 24; ++ks) {
    const int nxt = cur ^ 1;
    const bool more = (ks < 23);
    float4 a1a, a1b, a2a, a2b;
    f16x8 vh1, vh2;
    if (more) {
      const int ko = (ks + 1) * 32;
      a1a = *(const float4*)(asrc1 + ko);
      a1b = *(const float4*)(asrc1 + ko + 4);
      a2a = *(const float4*)(asrc2 + ko);
      a2b = *(const float4*)(asrc2 + ko + 4);
      vh1 = *(const f16x8*)(bh1 + ko);
      vh2 = *(const f16x8*)(bh2 + ko);
    }
    {
      const _Float16* Ab = &Al[cur][0];
      const _Float16* Bhb = &Bh[cur][0];
      f16x8 af[4], bhf[4];
#pragma unroll
      for (int fm = 0; fm < 4; ++fm) af[fm] = *(const f16x8*)&Ab[aoff[fm]];
#pragma unroll
      for (int fn = 0; fn < 4; ++fn) bhf[fn] = *(const f16x8*)&Bhb[boff[fn]];
#pragma unroll
      for (int fm = 0; fm < 4; ++fm)
#pragma unroll
        for (int fn = 0; fn < 4; ++fn)
          acc[fm][fn] = __builtin_amdgcn_mfma_f32_16x16x32_f16(af[fm], bhf[fn], acc[fm][fn], 0, 0, 0);
    }
    if (more) {
      f16x8 h1, h2;
      h1[0]=(_Float16)a1a.x; h1[1]=(_Float16)a1a.y; h1[2]=(_Float16)a1a.z; h1[3]=(_Float16)a1a.w;
      h1[4]=(_Float16)a1b.x; h1[5]=(_Float16)a1b.y; h1[6]=(_Float16)a1b.z; h1[7]=(_Float16)a1b.w;
      h2[0]=(_Float16)a2a.x; h2[1]=(_Float16)a2a.y; h2[2]=(_Float16)a2a.z; h2[3]=(_Float16)a2a.w;
      h2[4]=(_Float16)a2b.x; h2[5]=(_Float16)a2b.y; h2[6]=(_Float16)a2b.z; h2[7]=(_Float16)a2b.w;
      *(f16x8*)&Al[nxt][wA1] = h1;
      *(f16x8*)&Al[nxt][wA2] = h2;
      *(f16x8*)&Bh[nxt][wA1] = vh1;
      *(f16x8*)&Bh[nxt][wA2] = vh2;
    }
    barrier_lds_only();
    cur = nxt;
  }

  const int lq = lane >> 4;
  const int colbase = nt * 128 + wn * 64;
  const int ibase = mt * 128 + wm * 64;
  float* XUs = XU + (size_t)s * 4800 * 512;
  int rowm[4][4];
#pragma unroll
  for (int fm = 0; fm < 4; ++fm)
#pragma unroll
    for (int r = 0; r < 4; ++r) {
      const int i = ibase + fm * 16 + lq * 4 + r;
      rowm[fm][r] = (i < M) ? rms[i] : -1;
    }
#pragma unroll
  for (int fn = 0; fn < 4; ++fn) {
    const int col = colbase + fn * 16 + l15;
    const float bias = bU[s * 512 + col];
#pragma unroll
    for (int fm = 0; fm < 4; ++fm)
#pragma unroll
      for (int r = 0; r < 4; ++r) {
        const int row = rowm[fm][r];
        if (row >= 0) XUs[(size_t)row * 512 + col] = acc[fm][fn][r] + bias;
      }
  }
}

// ---------------------------------------------------------------------------
// K2 v9: MFMA time-LSTM (unchanged from round 16 / round 14 state).
// ---------------------------------------------------------------------------
__global__ __launch_bounds__(512, 2) void k2_tlstm(const _Float16* __restrict__ Wfh,
                                                   const _Float16* __restrict__ Dfh,
                                                   const float* __restrict__ ball,
                                                   const float* __restrict__ bd,
                                                   const float* __restrict__ XU,
                                                   const float* __restrict__ times,
                                                   const int* __restrict__ lens,
                                                   float* __restrict__ outs,
                                                   float* __restrict__ hn) {
  const int s = blockIdx.x;
  const int mg = blockIdx.y;
  const int tid = threadIdx.x;
  const int w = tid >> 6, l = tid & 63;

  __shared__ _Float16 hhb[2][2048];
  __shared__ _Float16 chb[2][2048];
  __shared__ float xut[2][16 * 516];
  __shared__ float tsh[16 * 32];
  __shared__ int lensh[16];

  if (tid < 16) {
    const int n = mg * 16 + tid;
    lensh[tid] = lens[((n / 5) * 8 + s) * 5 + (n % 5)];
  }
  if (tid < 480) {
    const int r = tid / 30, c = tid % 30;
    const int n = mg * 16 + r;
    tsh[r * 32 + c] = times[(((n / 5) * 8 + s) * 5 + (n % 5)) * 30 + c];
  }

  f16x8 Bh[16], Dh[4];
  {
    const _Float16* wb = Wfh + (size_t)(s * 8 + w) * 8192 + l * 8;
    const _Float16* db = Dfh + (size_t)(s * 8 + w) * 2048 + l * 8;
#pragma unroll
    for (int c = 0; c < 16; ++c) Bh[c] = *(const f16x8*)&wb[c * 512];
#pragma unroll
    for (int c = 0; c < 4; ++c) Dh[c] = *(const f16x8*)&db[c * 512];
  }

  const int hd = w * 16 + (l & 15);
  const int rq0 = (l >> 4) * 4;
  const int lp0 = rq0 | (((hd >> 3) & 3) << 4);
  const int eoff0 = ((hd >> 5) * 64 + lp0) * 8 + (hd & 7);

#pragma unroll
  for (int q = 0; q < 4; ++q) {
    hhb[0][eoff0 + q * 8] = (_Float16)0.f;
    chb[0][eoff0 + q * 8] = (_Float16)0.f;
  }

  int n_q[4];
#pragma unroll
  for (int q = 0; q < 4; ++q) n_q[q] = mg * 16 + rq0 + q;
  float blr[4];
#pragma unroll
  for (int g = 0; g < 4; ++g) blr[g] = ball[s * 512 + g * 128 + hd];
  const float bdj = bd[s * 128 + hd];

  const int sr = tid >> 5;
  const int sc = tid & 31;
  const float* xsrc = XU + (size_t)(s * 160 + mg * 16 + sr) * 30 * 512 + sc * 4;
  const int xdst = sr * 516 + sc * 4;

  __syncthreads();

  int len_q[4];
  int maxlen = 0;
#pragma unroll
  for (int i = 0; i < 16; ++i) maxlen = max(maxlen, lensh[i]);
#pragma unroll
  for (int q = 0; q < 4; ++q) len_q[q] = lensh[rq0 + q];

  float creg[4] = {0.f, 0.f, 0.f, 0.f};
  float hreg[4] = {0.f, 0.f, 0.f, 0.f};
  float oprev[4] = {0.f, 0.f, 0.f, 0.f};

  {
    float4 v0 = *(const float4*)(xsrc);
    float4 v1 = *(const float4*)(xsrc + 128);
    float4 v2 = *(const float4*)(xsrc + 256);
    float4 v3 = *(const float4*)(xsrc + 384);
    *(float4*)&xut[0][xdst]       = v0;
    *(float4*)&xut[0][xdst + 128] = v1;
    *(float4*)&xut[0][xdst + 256] = v2;
    *(float4*)&xut[0][xdst + 384] = v3;
  }
  __syncthreads();

  for (int t = 0; t < maxlen; ++t) {
    const int p = t & 1;

    if (t > 0) {
      const int tp = t - 1;
#pragma unroll
      for (int q = 0; q < 4; ++q) {
        if (tp < len_q[q]) {
          outs[((size_t)(s * 160 + n_q[q]) * 30 + tp) * 128 + hd] = oprev[q];
          if (tp == len_q[q] - 1) hn[(size_t)(s * 160 + n_q[q]) * 128 + hd] = oprev[q];
        }
      }
    }

    float4 pv0, pv1, pv2, pv3;
    const bool more = (t + 1 < maxlen);
    if (more) {
      const float* xp = xsrc + (size_t)(t + 1) * 512;
      pv0 = *(const float4*)(xp);
      pv1 = *(const float4*)(xp + 128);
      pv2 = *(const float4*)(xp + 256);
      pv3 = *(const float4*)(xp + 384);
    }

    f32x4 amA[4], amB[4], dm;
#pragma unroll
    for (int g = 0; g < 4; ++g) {
      amA[g] = (f32x4){0.f, 0.f, 0.f, 0.f};
      amB[g] = (f32x4){0.f, 0.f, 0.f, 0.f};
    }
    dm = (f32x4){0.f, 0.f, 0.f, 0.f};
#pragma unroll
    for (int kt = 0; kt < 2; ++kt) {
      const f16x8 ah0 = *(const f16x8*)&hhb[p][(kt * 64 + l) * 8];
      const f16x8 ah1 = *(const f16x8*)&hhb[p][((kt + 2) * 64 + l) * 8];
      const f16x8 cf0 = *(const f16x8*)&chb[p][(kt * 64 + l) * 8];
      const f16x8 cf1 = *(const f16x8*)&chb[p][((kt + 2) * 64 + l) * 8];
#pragma unroll
      for (int g = 0; g < 4; ++g) {
        amA[g] = __builtin_amdgcn_mfma_f32_16x16x32_f16(ah0, Bh[kt * 4 + g], amA[g], 0, 0, 0);
        amB[g] = __builtin_amdgcn_mfma_f32_16x16x32_f16(ah1, Bh[(kt + 2) * 4 + g], amB[g], 0, 0, 0);
      }
      dm = __builtin_amdgcn_mfma_f32_16x16x32_f16(cf0, Dh[kt], dm, 0, 0, 0);
      dm = __builtin_amdgcn_mfma_f32_16x16x32_f16(cf1, Dh[kt + 2], dm, 0, 0, 0);
    }

#pragma unroll
    for (int q = 0; q < 4; ++q) {
      if (t < len_q[q]) {
        const float* xr = &xut[p][(rq0 + q) * 516 + hd];
        const float tt = tsh[(rq0 + q) * 32 + t];
        const float cs1 = tanhf_(dm[q] + bdj);
        const float f  = sigf(amA[0][q] + amB[0][q] + xr[0]   + blr[0]);
        const float ii = sigf(amA[1][q] + amB[1][q] + xr[128] + blr[1]);
        const float o  = sigf(amA[2][q] + amB[2][q] + xr[256] + blr[2]);
        const float ct = sigf(amA[3][q] + amB[3][q] + xr[384] + blr[3]);
        const float c2 = f * (creg[q] + cs1 * (tt - 1.f)) + ii * ct;
        creg[q] = c2;
        hreg[q] = o * tanhf_(c2);
        oprev[q] = o;
      }
      hhb[p ^ 1][eoff0 + q * 8] = (_Float16)hreg[q];
      chb[p ^ 1][eoff0 + q * 8] = (_Float16)creg[q];
    }

    if (more) {
      *(float4*)&xut[p ^ 1][xdst]       = pv0;
      *(float4*)&xut[p ^ 1][xdst + 128] = pv1;
      *(float4*)&xut[p ^ 1][xdst + 256] = pv2;
      *(float4*)&xut[p ^ 1][xdst + 384] = pv3;
    }
    barrier_lds_only();
  }

  {
    const int tp = maxlen - 1;
#pragma unroll
    for (int q = 0; q < 4; ++q) {
      if (tp >= 0 && tp < len_q[q]) {
        outs[((size_t)(s * 160 + n_q[q]) * 30 + tp) * 128 + hd] = oprev[q];
        if (tp == len_q[q] - 1) hn[(size_t)(s * 160 + n_q[q]) * 128 + hd] = oprev[q];
      }
    }
  }
}

// ---------------------------------------------------------------------------
// K3 v7: MFMA attention-1 with LDS-staged o-tile (unchanged).
// ---------------------------------------------------------------------------
__global__ __launch_bounds__(512, 2) void k3_attn1(const _Float16* __restrict__ W1f,
                                                   const _Float16* __restrict__ W2f,
                                                   const float* __restrict__ b1,
                                                   const float* __restrict__ b2,
                                                   const float* __restrict__ V,
                                                   const float* __restrict__ outs,
                                                   const float* __restrict__ hn,
                                                   const int* __restrict__ lens,
                                                   float* __restrict__ ctx) {
  const int s = blockIdx.x;
  const int sg = blockIdx.y;
  const int tid = threadIdx.x;
  const int w = tid >> 6, l = tid & 63;
  const int nbase = s * 160 + sg * 8;

  __shared__ _Float16 osh[32768];
  __shared__ float u[16][132];
  __shared__ float red[8][8][32];
  __shared__ float score[8][32];
  __shared__ int lensh[8];

  if (tid < 8) {
    const int n = sg * 8 + tid;
    lensh[tid] = lens[((n / 5) * 8 + s) * 5 + (n % 5)];
  }

#pragma unroll
  for (int i = 0; i < 8; ++i) {
    const int c = tid + i * 512;
    const int nl = c >> 9;
    const int th = (c >> 8) & 1;
    const int kt = (c >> 6) & 3;
    const int lp = c & 63;
    const int t15 = lp & 15;
    const int kb = kt * 32 + (lp >> 4) * 8;
    const int t = th * 16 + t15;
    f16x8 v;
    if (t < 30) {
      const float* src = outs + ((size_t)(nbase + nl) * 30 + t) * 128 + kb;
      const float4 a = *(const float4*)(src);
      const float4 b = *(const float4*)(src + 4);
      v[0]=(_Float16)a.x; v[1]=(_Float16)a.y; v[2]=(_Float16)a.z; v[3]=(_Float16)a.w;
      v[4]=(_Float16)b.x; v[5]=(_Float16)b.y; v[6]=(_Float16)b.z; v[7]=(_Float16)b.w;
    } else {
      v = (f16x8){(_Float16)0.f,(_Float16)0.f,(_Float16)0.f,(_Float16)0.f,
                  (_Float16)0.f,(_Float16)0.f,(_Float16)0.f,(_Float16)0.f};
    }
    *(f16x8*)&osh[c * 8] = v;
  }

  f16x8 W1r[4], W2r[4];
  {
    const _Float16* w1b = W1f + (size_t)(s * 8 + w) * 2048 + l * 8;
    const _Float16* w2b = W2f + (size_t)(s * 8 + w) * 2048 + l * 8;
#pragma unroll
    for (int kt = 0; kt < 4; ++kt) {
      W1r[kt] = *(const f16x8*)&w1b[kt * 512];
      W2r[kt] = *(const f16x8*)&w2b[kt * 512];
    }
  }

  const int hd = w * 16 + (l & 15);
  const float Vhd = V[s * 128 + hd];
  const float b12 = b1[s * 128 + hd] + b2[s * 128 + hd];
  const int kc = (l >> 4) << 3;

  {
    const int rsrc = min(l & 15, 7);
    f32x4 dm = (f32x4){0.f, 0.f, 0.f, 0.f};
#pragma unroll
    for (int kt = 0; kt < 4; ++kt) {
      const float* hp = hn + (size_t)(nbase + rsrc) * 128 + kt * 32 + kc;
      const float4 a = *(const float4*)(hp);
      const float4 b = *(const float4*)(hp + 4);
      f16x8 ah;
      ah[0]=(_Float16)a.x; ah[1]=(_Float16)a.y; ah[2]=(_Float16)a.z; ah[3]=(_Float16)a.w;
      ah[4]=(_Float16)b.x; ah[5]=(_Float16)b.y; ah[6]=(_Float16)b.z; ah[7]=(_Float16)b.w;
      dm = __builtin_amdgcn_mfma_f32_16x16x32_f16(ah, W1r[kt], dm, 0, 0, 0);
    }
#pragma unroll
    for (int q = 0; q < 4; ++q) u[(l >> 4) * 4 + q][hd] = dm[q] + b12;
  }
  __syncthreads();

#pragma unroll
  for (int m = 0; m < 16; ++m) {
    const int nl = m >> 1, th = m & 1;
    const int cbase = ((nl * 2 + th) * 4) * 64;
    f32x4 acc = (f32x4){0.f, 0.f, 0.f, 0.f};
#pragma unroll
    for (int kt = 0; kt < 4; ++kt) {
      const f16x8 ah = *(const f16x8*)&osh[(cbase + kt * 64 + l) * 8];
      acc = __builtin_amdgcn_mfma_f32_16x16x32_f16(ah, W2r[kt], acc, 0, 0, 0);
    }
    const float uv = u[nl][hd];
#pragma unroll
    for (int q = 0; q < 4; ++q) {
      float p = tanhf_(acc[q] + uv) * Vhd;
      p += __shfl_xor(p, 1);
      p += __shfl_xor(p, 2);
      p += __shfl_xor(p, 4);
      p += __shfl_xor(p, 8);
      const int t = th * 16 + (l >> 4) * 4 + q;
      if ((l & 15) == 0 && t < 30) red[w][nl][t] = p;
    }
  }
  __syncthreads();

  if (tid < 256) {
    const int nl = tid >> 5, t = tid & 31;
    if (t < 30) {
      float sc = 0.f;
#pragma unroll
      for (int ww = 0; ww < 8; ++ww) sc += red[ww][nl][t];
      score[nl][t] = sc;
    }
  }
  __syncthreads();

  {
    const int nl = tid >> 6, jg = tid & 63;
    const int len = lensh[nl];
    float mx = -1e30f;
    for (int t = 0; t < len; ++t) mx = fmaxf(mx, score[nl][t]);
    const float* ob = outs + (size_t)(nbase + nl) * 30 * 128 + jg * 2;
    float sum = 0.f;
    float cx0 = 0.f, cx1 = 0.f;
    for (int t = 0; t < len; ++t) {
      const float e = __expf(score[nl][t] - mx);
      sum += e;
      const float2 o2 = *(const float2*)(ob + (size_t)t * 128);
      cx0 += e * o2.x; cx1 += e * o2.y;
    }
    const float r = rcp_(sum);
    float2 res = {cx0 * r, cx1 * r};
    *(float2*)&ctx[(size_t)(nbase + nl) * 128 + jg * 2] = res;
  }
}

// ---------------------------------------------------------------------------
// K45: FUSED lstm2 + attention2 + output MLP. One block per (s, b), 512 thr.
//   Phase 1 (= old k4): LSTM over D=5, hsm[5][128] kept in LDS; the global
//   hsout/hlast round-trip is deleted (k5 was its only consumer).
//   Phase 2 (= old k5, re-parallelized): every dot-product 4-way k-split
//   across 512 threads + LDS reduce; bV dropped (softmax-invariant).
// ---------------------------------------------------------------------------
__global__ __launch_bounds__(512, 2) void k45_fused(const float* __restrict__ Wih,
                                                    const float* __restrict__ bih,
                                                    const float* __restrict__ Whh,
                                                    const float* __restrict__ bhh,
                                                    const float* __restrict__ aW1,
                                                    const float* __restrict__ ab1,
                                                    const float* __restrict__ aW2,
                                                    const float* __restrict__ ab2,
                                                    const float* __restrict__ aV,
                                                    const float* __restrict__ x1W,
                                                    const float* __restrict__ x1b,
                                                    const float* __restrict__ x2W,
                                                    const float* __restrict__ x2b,
                                                    const float* __restrict__ ctx,
                                                    float* __restrict__ y) {
  const int s = blockIdx.y, b = blockIdx.x;
  const int tid = threadIdx.x;
  __shared__ float xs[5][128];
  __shared__ float hsm[5][128];
  __shared__ float hcur[128];
  __shared__ float gsh[512];
  __shared__ float red[4][128];
  __shared__ float wred[2];
  __shared__ float sc[5];
  __shared__ float u_sh[128];
  __shared__ float cs2[128];
  __shared__ float t1[128];
  __shared__ float red2[8][64];

  // ---- phase 1: LSTM over D=5 (gate split i,f,g,o; tanh on g) ----
  for (int idx = tid; idx < 640; idx += 512)
    (&xs[0][0])[idx] = ctx[(size_t)(s * 160 + b * 5) * 128 + idx];
  if (tid < 128) hcur[tid] = 0.f;
  __syncthreads();

  const float* Wis = Wih + (size_t)s * 65536;
  const float* Whs = Whh + (size_t)s * 65536;
  const float bias = bih[s * 512 + tid] + bhh[s * 512 + tid];
  float xw[5] = {bias, bias, bias, bias, bias};
  float whh[128];
#pragma unroll
  for (int k = 0; k < 128; ++k) {
    const float wi = Wis[k * 512 + tid];
    whh[k] = Whs[k * 512 + tid];
#pragma unroll
    for (int dd = 0; dd < 5; ++dd) xw[dd] += xs[dd][k] * wi;
  }

  float c = 0.f;
  for (int dd = 0; dd < 5; ++dd) {
    float g = xw[dd];
#pragma unroll
    for (int k = 0; k < 128; ++k) g += hcur[k] * whh[k];
    gsh[tid] = g;
    __syncthreads();
    if (tid < 128) {
      const int j = tid;
      const float c2 = sigf(gsh[128 + j]) * c + sigf(gsh[j]) * tanhf_(gsh[256 + j]);
      const float h2 = sigf(gsh[384 + j]) * tanhf_(c2);
      c = c2;
      hcur[j] = h2;
      hsm[dd][j] = h2;
    }
    __syncthreads();
  }

  // ---- phase 2: attention 2 + MLP, 4-way k-splits ----
  const int q = tid >> 7, j = tid & 127;
  const float* W1s = aW1 + (size_t)s * 16384;
  const float* W2s = aW2 + (size_t)s * 16384;

  // u = hlast @ W1 + b1 + b2
  {
    float part = 0.f;
#pragma unroll
    for (int k = 0; k < 32; ++k) part += hsm[4][q * 32 + k] * W1s[(q * 32 + k) * 128 + j];
    red[q][j] = part;
  }
  __syncthreads();
  if (tid < 128)
    u_sh[j] = red[0][j] + red[1][j] + red[2][j] + red[3][j] +
              ab1[s * 128 + j] + ab2[s * 128 + j];
  __syncthreads();

  // scores (bV omitted: softmax-invariant)
  for (int d = 0; d < 5; ++d) {
    float part = 0.f;
#pragma unroll
    for (int k = 0; k < 32; ++k) part += hsm[d][q * 32 + k] * W2s[(q * 32 + k) * 128 + j];
    red[q][j] = part;
    __syncthreads();
    if (tid < 128) {
      float a = u_sh[j] + red[0][j] + red[1][j] + red[2][j] + red[3][j];
      float pv = tanhf_(a) * aV[s * 128 + j];
#pragma unroll
      for (int off = 32; off; off >>= 1) pv += __shfl_down(pv, off);
      if ((tid & 63) == 0) wred[tid >> 6] = pv;
    }
    __syncthreads();
    if (tid == 0) sc[d] = wred[0] + wred[1];
    __syncthreads();
  }

  // softmax over 5 + cs2
  if (tid < 128) {
    float m = sc[0];
#pragma unroll
    for (int d = 1; d < 5; ++d) m = fmaxf(m, sc[d]);
    float e[5], sum = 0.f;
#pragma unroll
    for (int d = 0; d < 5; ++d) { e[d] = __expf(sc[d] - m); sum += e[d]; }
    float cx = 0.f;
#pragma unroll
    for (int d = 0; d < 5; ++d) cx += e[d] * hsm[d][j];
    cs2[j] = cx * rcp_(sum);
  }
  __syncthreads();

  // t1 = relu(cs2 @ x1W + x1b)
  {
    float part = 0.f;
#pragma unroll
    for (int k = 0; k < 32; ++k) part += cs2[q * 32 + k] * x1W[(size_t)s * 16384 + (q * 32 + k) * 128 + j];
    red[q][j] = part;
  }
  __syncthreads();
  if (tid < 128)
    t1[j] = fmaxf(red[0][j] + red[1][j] + red[2][j] + red[3][j] + x1b[s * 128 + j], 0.f);
  __syncthreads();

  // y = t1 @ x2W + x2b (8-way k-split over 64 cols)
  {
    const int q2 = tid >> 6, j2 = tid & 63;
    float part = 0.f;
#pragma unroll
    for (int k = 0; k < 16; ++k) part += t1[q2 * 16 + k] * x2W[(size_t)s * 8192 + (q2 * 16 + k) * 64 + j2];
    red2[q2][j2] = part;
  }
  __syncthreads();
  if (tid < 64) {
    float yy = x2b[s * 64 + tid];
#pragma unroll
    for (int g = 0; g < 8; ++g) yy += red2[g][tid];
    y[(size_t)(s * 32 + b) * 64 + tid] = yy;
  }
}

// ---------------------------------------------------------------------------
// K6: final combine (unchanged).
// ---------------------------------------------------------------------------
__global__ __launch_bounds__(256) void k6_final(const float* __restrict__ stock,
                                                const float* __restrict__ h1W,
                                                const float* __restrict__ h1b,
                                                const float* __restrict__ h2W,
                                                const float* __restrict__ h2b,
                                                const float* __restrict__ hcW,
                                                const float* __restrict__ hcb,
                                                const float* __restrict__ yws,
                                                float* __restrict__ out) {
  const int tid = threadIdx.x;
  __shared__ float sf[32 * 17];
  __shared__ float hid[32 * 64];
  __shared__ float xs[32 * 32];
  for (int idx = tid; idx < 544; idx += 256) sf[idx] = stock[idx];
  __syncthreads();
  for (int idx = tid; idx < 2048; idx += 256) {
    const int b = idx >> 6, k = idx & 63;
    float a = h1b[k];
    for (int q = 0; q < 17; ++q) a += sf[b * 17 + q] * h1W[q * 64 + k];
    hid[idx] = fmaxf(a, 0.f);
  }
  __syncthreads();
  for (int idx = tid; idx < 1024; idx += 256) {
    const int b = idx >> 5, mm = idx & 31;
    float a = h2b[mm];
    for (int k = 0; k < 64; ++k) a += hid[b * 64 + k] * h2W[k * 32 + mm];
    xs[idx] = a;
  }
  __syncthreads();
  {
    const int b = tid >> 3, o = tid & 7;
    float a = hcb[o];
    for (int c = 0; c < 32; ++c) a += xs[b * 32 + c] * hcW[c * 8 + o];
    for (int c = 32; c < 544; ++c) {
      const int ss = (c - 32) >> 6, k = (c - 32) & 63;
      a += yws[((size_t)ss * 32 + b) * 64 + k] * hcW[c * 8 + o];
    }
    out[tid] = tanhf_(a);
  }
}

// ---------------------------------------------------------------------------
extern "C" void kernel_launch(void* const* d_in, const int* in_sizes, int n_in,
                              void* d_out, int out_size, void* d_ws, size_t ws_size,
                              hipStream_t stream) {
  (void)in_sizes; (void)n_in; (void)out_size; (void)ws_size;
  const float* stock = (const float*)d_in[0];
  const float* sent  = (const float*)d_in[1];
  const float* times = (const float*)d_in[2];
  const int*   lens  = (const int*)d_in[3];
  const float* tlWall = (const float*)d_in[4];
  const float* tlball = (const float*)d_in[5];
  const float* tlUall = (const float*)d_in[6];
  const float* tlbU   = (const float*)d_in[7];
  const float* tlWd   = (const float*)d_in[8];
  const float* tlbd   = (const float*)d_in[9];
  const float* a1W1 = (const float*)d_in[10];
  const float* a1b1 = (const float*)d_in[11];
  const float* a1W2 = (const float*)d_in[12];
  const float* a1b2 = (const float*)d_in[13];
  const float* a1V  = (const float*)d_in[14];
  const float* a1bV = (const float*)d_in[15];
  const float* l2Wih = (const float*)d_in[16];
  const float* l2bih = (const float*)d_in[17];
  const float* l2Whh = (const float*)d_in[18];
  const float* l2bhh = (const float*)d_in[19];
  const float* a2W1 = (const float*)d_in[20];
  const float* a2b1 = (const float*)d_in[21];
  const float* a2W2 = (const float*)d_in[22];
  const float* a2b2 = (const float*)d_in[23];
  const float* a2V  = (const float*)d_in[24];
  const float* a2bV = (const float*)d_in[25];
  const float* x1W  = (const float*)d_in[26];
  const float* x1b  = (const float*)d_in[27];
  const float* x2W  = (const float*)d_in[28];
  const float* x2b  = (const float*)d_in[29];
  const float* h1W  = (const float*)d_in[30];
  const float* h1b  = (const float*)d_in[31];
  const float* h2W  = (const float*)d_in[32];
  const float* h2b  = (const float*)d_in[33];
  const float* hcW  = (const float*)d_in[34];
  const float* hcb  = (const float*)d_in[35];
  (void)a1bV; (void)a2bV;

  float* ws = (float*)d_ws;
  float* XU    = ws;               // 8*160*30*512   = 19,660,800
  float* outs  = XU + 19660800;    // 8*160*30*128   =  4,915,200
  float* hnb   = outs + 4915200;   // 8*160*128      =    163,840
  float* ctx   = hnb + 163840;     // 8*160*128      =    163,840
  float* yb    = ctx + 163840;     // 8*32*64        =     16,384
  _Float16* Uhw = (_Float16*)(yb + 16384);    // 8*512*768 halfs
  _Float16* Wfh = Uhw + 8 * 512 * 768;        // 8*8*8192 halfs
  _Float16* Dfh = Wfh + 8 * 8 * 8192;         // 8*8*2048 halfs
  _Float16* W1f = Dfh + 8 * 8 * 2048;         // 8*8*2048 halfs
  _Float16* W2f = W1f + 8 * 8 * 2048;         // 8*8*2048 halfs
  int* rowmap = (int*)(W2f + 8 * 8 * 2048);   // 8*4800 ints
  int* Msd    = rowmap + 8 * 4800;            // 8 ints

  k0_rowmap<<<8, 256, 0, stream>>>(lens, rowmap, Msd);
  k0_usplit<<<dim3(12, 8, 8), 256, 0, stream>>>(tlUall, Uhw);
  k0_wprep<<<dim3(8, 8), 256, 0, stream>>>(tlWall, tlWd, Wfh, Dfh);
  k0_aprep<<<dim3(8, 8), 256, 0, stream>>>(a1W1, a1W2, W1f, W2f);
  k1_xu<<<dim3(8, 152), 256, 0, stream>>>(sent, Uhw, tlbU, rowmap, Msd, XU);
  k2_tlstm<<<dim3(8, 10), 512, 0, stream>>>(Wfh, Dfh, tlball, tlbd, XU, times, lens, outs, hnb);
  k3_attn1<<<dim3(8, 20), 512, 0, stream>>>(W1f, W2f, a1b1, a1b2, a1V, outs, hnb, lens, ctx);
  k45_fused<<<dim3(32, 8), 512, 0, stream>>>(l2Wih, l2bih, l2Whh, l2bhh,
                                             a2W1, a2b1, a2W2, a2b2, a2V,
                                             x1W, x1b, x2W, x2b, ctx, yb);
  k6_final<<<1, 256, 0, stream>>>(stock, h1W, h1b, h2W, h2b, hcW, hcb, yb, (float*)d_out);
}